// Round 19
// baseline (128.776 us; speedup 1.0000x reference)
//
#include <hip/hip_runtime.h>
#include <hip/hip_bf16.h>

#define B_    32
#define T_    256
#define C_    512
#define H_    512
#define TOUT_ 2048
#define TP_   258        // padded time length (zero row at t=0 and t=257)
#define K_    1536       // 3 * 512
#define EPS_  1e-5f

typedef __attribute__((ext_vector_type(8))) short bf16x8;
typedef __attribute__((ext_vector_type(4))) float f32x4;

#define GLL16(g, l)                                                        \
  __builtin_amdgcn_global_load_lds(                                        \
      (const __attribute__((address_space(1))) void*)(g),                  \
      (__attribute__((address_space(3))) void*)(l), 16, 0, 0)

// ---------------------------------------------------------------------------
// helpers (256-thread sub-tid where noted)
// ---------------------------------------------------------------------------
__device__ __forceinline__ void wt_convert_block(const float* __restrict__ W,
                                                 __hip_bfloat16* __restrict__ Wt,
                                                 int k0, int n0, int tid,
                                                 float* tile /* [32][33] */) {
  const int tx = tid & 31;
  const int ty = tid >> 5;
#pragma unroll
  for (int i = 0; i < 4; ++i)
    tile[(ty * 4 + i) * 33 + tx] = W[(size_t)(k0 + ty * 4 + i) * H_ + n0 + tx];
  __syncthreads();
#pragma unroll
  for (int i = 0; i < 4; ++i)
    Wt[(size_t)(n0 + ty * 4 + i) * K_ + k0 + tx] =
        __float2bfloat16(tile[tx * 33 + ty * 4 + i]);
}

// inclusive scan of one batch's 256 durations -> csum (256-thread block)
__device__ __forceinline__ void csum_block(const int* __restrict__ dur,
                                           int* __restrict__ csum,
                                           int b, int tid, int* wsum) {
  int v = dur[b * T_ + tid];
#pragma unroll
  for (int off = 1; off < 64; off <<= 1) {
    int u = __shfl_up(v, off);
    if ((tid & 63) >= off) v += u;
  }
  if ((tid & 63) == 63) wsum[tid >> 6] = v;
  __syncthreads();
  int base = 0;
#pragma unroll
  for (int j = 0; j < 4; ++j)
    if (j < (tid >> 6)) base += wsum[j];
  csum[b * T_ + tid] = v + base;
}

// copy unit: 16 source rows; read row once, write its d output rows
__device__ __forceinline__ void expand_copy_block(const float* __restrict__ X,
                                                  const int* __restrict__ csum,
                                                  float* __restrict__ res,
                                                  int u, int tid) {
  const int wave = (tid >> 6) & 3, lane = tid & 63;
#pragma unroll
  for (int k = 0; k < 4; ++k) {
    const int sr = u * 16 + wave * 4 + k;    // 0..8191
    const int b = sr >> 8, t = sr & 255;
    const int* cb = csum + b * T_;
    const int c0 = t ? cb[t - 1] : 0;
    const int d  = cb[t] - c0;
    if (d == 0) continue;
    const float* src = X + (size_t)sr * C_;
    const float4 v0 = *(const float4*)(src + lane * 4);
    const float4 v1 = *(const float4*)(src + 256 + lane * 4);
    float* dst = res + ((size_t)b * TOUT_ + c0) * C_;
    for (int j = 0; j < d; ++j) {
      *(float4*)(dst + (size_t)j * C_ + lane * 4)       = v0;
      *(float4*)(dst + (size_t)j * C_ + 256 + lane * 4) = v1;
    }
  }
}

// zero unit: 32 output rows of one batch, zero those >= total
__device__ __forceinline__ void expand_zero_block(const int* __restrict__ csum,
                                                  float* __restrict__ res,
                                                  int z, int tid) {
  const int b  = z >> 6;
  const int t0 = (z & 63) << 5;
  const int total = csum[b * T_ + 255];
  const float4 z4 = make_float4(0.f, 0.f, 0.f, 0.f);
  const int half = (tid >> 7) & 1, c4 = tid & 127;
#pragma unroll
  for (int rr = half; rr < 32; rr += 2) {
    const int r = t0 + rr;
    if (r >= total)
      *(float4*)(res + ((size_t)b * TOUT_ + r) * C_ + c4 * 4) = z4;
  }
}

// ---------------------------------------------------------------------------
// 1) prep (256 threads): cvt_x_pad (0..4127) + cvt W1 (4128..4895) + csum
// ---------------------------------------------------------------------------
__global__ __launch_bounds__(256) void prep_kernel(const float* __restrict__ X,
                                                   const float* __restrict__ W1,
                                                   const int* __restrict__ dur,
                                                   __hip_bfloat16* __restrict__ xpad,
                                                   __hip_bfloat16* __restrict__ hpad,
                                                   __hip_bfloat16* __restrict__ Wt1,
                                                   int* __restrict__ csum) {
  __shared__ float tile[32 * 33];
  const int tid = threadIdx.x;
  if (blockIdx.x >= 4896) {
    csum_block(dur, csum, blockIdx.x - 4896, tid, (int*)tile);
    return;
  }
  if (blockIdx.x >= 4128) {
    const int id = blockIdx.x - 4128;       // 0..767
    wt_convert_block(W1, Wt1, (id % 48) * 32, (id / 48) * 32, tid, tile);
    return;
  }
  const int row = blockIdx.x * 2 + (tid >> 7);   // 0..8255
  const int b = row / TP_;
  const int t = row - b * TP_;
  const int c = (tid & 127) * 4;
  __hip_bfloat16* dst = xpad + (size_t)row * C_ + c;
  if (t == 0 || t == TP_ - 1) {
    ushort4 zz = make_ushort4(0, 0, 0, 0);
    *(ushort4*)dst = zz;
    *(ushort4*)(hpad + (size_t)row * C_ + c) = zz;
    return;
  }
  const float4 v = *(const float4*)(X + (size_t)(b * T_ + t - 1) * C_ + c);
  union { __hip_bfloat16 h[4]; ushort4 u; } o;
  o.h[0] = __float2bfloat16(v.x);
  o.h[1] = __float2bfloat16(v.y);
  o.h[2] = __float2bfloat16(v.z);
  o.h[3] = __float2bfloat16(v.w);
  *(ushort4*)dst = o.u;
}

// ---------------------------------------------------------------------------
// 2) heterogeneous, 512 threads/block, __launch_bounds__(512,1) (256 VGPRs —
//    acc[4][8]=128 regs must NOT spill; R16's failure was (512,2)'s 128-cap):
//    conv+LN fused (0..63) || expand (64..703, 2 units/block)
//    || optional W2 transpose (704.., 2 tiles/block, first dispatch only)
//    conv: 128(M) x 512(N) full-row tile, BK=32, 48 steps, 8 waves of
//    64x128, 2-buf ring (80 KB LDS), counted vmcnt(5), line-coalesced
//    staging with period-8 slot swizzle. Epilogue fuses bias+LN(+ReLU):
//    MODE 0 -> bf16 hpad; MODE 1 -> linear head -> loglen.
// ---------------------------------------------------------------------------
template <int MODE>
__global__ __launch_bounds__(512, 1) void conv_fused_kernel(
    const __hip_bfloat16* __restrict__ Apad,   // [32*258, 512]
    const __hip_bfloat16* __restrict__ Wt,     // [512, 1536]
    const float* __restrict__ bias,            // [512]
    const float* __restrict__ gam,             // [512]
    const float* __restrict__ bet,             // [512]
    const float* __restrict__ Wl,              // [512] (MODE 1)
    const float* __restrict__ bl,              // [1]   (MODE 1)
    __hip_bfloat16* __restrict__ hout,         // MODE 0 out (padded bf16)
    float* __restrict__ lout,                  // MODE 1 out (loglen)
    const float* __restrict__ X,               // f32 input (for expand)
    const int* __restrict__ csum,
    float* __restrict__ res,
    const float* __restrict__ W2,              // may be null
    __hip_bfloat16* __restrict__ Wt2,          // may be null
    int ex_base) {
  __shared__ __hip_bfloat16 smA[2][4096];      // [buf][row128*32] = 16 KB
  __shared__ __hip_bfloat16 smB[2][16384];     // [buf][row512*32] = 64 KB

  const int tid = threadIdx.x;                 // 0..511

  if (blockIdx.x >= 704) {                     // W2 transpose: 2 tiles/block
    const int id = (blockIdx.x - 704) * 2 + (tid >> 8);   // 0..767
    float* tile = (float*)&smB[0][0] + (tid >> 8) * (32 * 33);
    wt_convert_block(W2, Wt2, (id % 48) * 32, (id / 48) * 32, tid & 255, tile);
    return;
  }
  if (blockIdx.x >= 64) {                      // expand: 2 units/block
    const int u = ex_base + (blockIdx.x - 64) * 2 + (tid >> 8);
    const int st = tid & 255;
    if (u < 512) expand_copy_block(X, csum, res, u, st);
    else         expand_zero_block(csum, res, u - 512, st);
    return;
  }

  // ---- conv GEMM path: 128(M) x 512(N), 8 waves of 64x128 ----
  const int lane = tid & 63;
  const int wid  = tid >> 6;                   // 0..7
  const int m0 = blockIdx.x << 7;              // 0..8064
  const int b  = m0 >> 8;
  const int t0 = m0 & 255;                     // 0 or 128
  const int wgrp   = wid >> 2;                 // 0/1 -> wm
  const int wslice = wid & 3;                  // 0..3 -> wn
  const int wm  = wgrp << 6;                   // 0 / 64
  const int wnn = wslice << 7;                 // 0,128,256,384

  // staging: 4 lanes/row, 16B each; fetch slice (slot + (row>>1)) & 3.
  // A rows: tid>>2 (0..127). B rows: (tid>>2) + 128j — 128j ≡ 0 mod 2·4,
  // so the slice formula is j-free on the fetch side too.
  const int rowS = tid >> 2;                   // 0..127
  const int gsw  = ((tid & 3) + (rowS >> 1)) & 3;
  const __hip_bfloat16* arowA = Apad + (size_t)(b * TP_ + t0 + rowS) * C_ + (gsw << 3);
  const __hip_bfloat16* browB = Wt + (size_t)rowS * K_ + (gsw << 3);  // +j*128 rows

  f32x4 acc[4][8] = {};

  // 5 GLL16/thread/step: 1 A + 4 B rounds (rows rowS + j*128)
  auto stage = [&](int buf, int k0) {
    const int kw = k0 >> 9;                    // conv window 0..2
    const int c0 = k0 & 511;
    GLL16(arowA + kw * C_ + c0, &smA[buf][tid << 3]);
#pragma unroll
    for (int j = 0; j < 4; ++j)
      GLL16(browB + (size_t)(j * 128) * K_ + k0,
            &smB[buf][(tid << 3) + (j << 12)]);
  };

  auto compute = [&](int buf) {
    const int g   = lane >> 4;
    const int r15 = lane & 15;
    const int sa  = ((g - (r15 >> 1)) & 3) << 3;   // swizzled slot (elems)
    bf16x8 aF[4], bF[8];
#pragma unroll
    for (int i = 0; i < 4; ++i)
      aF[i] = *(const bf16x8*)(&smA[buf][((wm + (i << 4) + r15) << 5) + sa]);
#pragma unroll
    for (int i = 0; i < 8; ++i)
      bF[i] = *(const bf16x8*)(&smB[buf][((wnn + (i << 4) + r15) << 5) + sa]);
#pragma unroll
    for (int mi = 0; mi < 4; ++mi)
#pragma unroll
      for (int ni = 0; ni < 8; ++ni)
        acc[mi][ni] = __builtin_amdgcn_mfma_f32_16x16x32_bf16(
            aF[mi], bF[ni], acc[mi][ni], 0, 0, 0);
  };

  // prologue: clean baseline, prefetch 2 tiles (10 vmem/wave in flight)
  asm volatile("s_waitcnt vmcnt(0)" ::: "memory");
  stage(0, 0);
  stage(1, 32);

  // main loop: compute steps 0..45, stage steps 2..47 (step s -> buf s&1)
  for (int s = 0; s < 46; ++s) {
    asm volatile("s_waitcnt vmcnt(5)" ::: "memory");   // oldest step's 5 done
    __builtin_amdgcn_sched_barrier(0);
    __builtin_amdgcn_s_barrier();
    compute(s & 1);
    asm volatile("s_waitcnt lgkmcnt(0)" ::: "memory");
    __builtin_amdgcn_s_barrier();
    stage(s & 1, (s + 2) << 5);
  }
  // tail: steps 46 (buf0), 47 (buf1) — drain 5 -> 0
  asm volatile("s_waitcnt vmcnt(5)" ::: "memory");
  __builtin_amdgcn_sched_barrier(0);
  __builtin_amdgcn_s_barrier();
  compute(0);
  asm volatile("s_waitcnt vmcnt(0)" ::: "memory");
  __builtin_amdgcn_sched_barrier(0);
  __builtin_amdgcn_s_barrier();
  compute(1);

  // ---- fused bias + LayerNorm epilogue ----
  __syncthreads();                             // done reading LDS buffers
  float* scr  = (float*)&smA[0][0];            // sq: [128][4][2] = 1024 f32
  float* scr2 = scr + 2048;                    // dot: [128][4] = 512 f32

  const int g   = lane >> 4;
  const int r15 = lane & 15;

  float bb8[8];
#pragma unroll
  for (int ni = 0; ni < 8; ++ni) bb8[ni] = bias[wnn + (ni << 4) + r15];

  // phase 1: per-row sum / sumsq across this wave's 128 cols
#pragma unroll
  for (int mi = 0; mi < 4; ++mi)
#pragma unroll
    for (int rq = 0; rq < 4; ++rq) {
      float s = 0.f, q = 0.f;
#pragma unroll
      for (int ni = 0; ni < 8; ++ni) {
        const float v = acc[mi][ni][rq] + bb8[ni];
        s += v; q += v * v;
      }
#pragma unroll
      for (int off = 1; off < 16; off <<= 1) {
        s += __shfl_xor(s, off);
        q += __shfl_xor(q, off);
      }
      if (r15 == 0) {
        const int lrow = (mi << 4) + (g << 2) + rq;      // 0..63
        const int base = (((wgrp << 6) + lrow) << 3) + (wslice << 1);
        scr[base]     = s;
        scr[base + 1] = q;
      }
    }
  __syncthreads();

  float g8[8], e8[8];
#pragma unroll
  for (int ni = 0; ni < 8; ++ni) {
    g8[ni] = gam[wnn + (ni << 4) + r15];
    e8[ni] = bet[wnn + (ni << 4) + r15];
  }
  float wl8[8];
  if (MODE == 1) {
#pragma unroll
    for (int ni = 0; ni < 8; ++ni) wl8[ni] = Wl[wnn + (ni << 4) + r15];
  }

  // phase 2: per-row mu/var, then normalize+relu (+ dot for MODE 1)
#pragma unroll
  for (int mi = 0; mi < 4; ++mi)
#pragma unroll
    for (int rq = 0; rq < 4; ++rq) {
      const int lrow = (mi << 4) + (g << 2) + rq;
      const int base = ((wgrp << 6) + lrow) << 3;
      const float S = scr[base] + scr[base + 2] + scr[base + 4] + scr[base + 6];
      const float Q = scr[base + 1] + scr[base + 3] + scr[base + 5] + scr[base + 7];
      const float mu  = S * (1.0f / 512.0f);
      const float var = Q * (1.0f / 512.0f) - mu * mu;
      const float rsv = rsqrtf(var + EPS_);
      if (MODE == 0) {
        __hip_bfloat16* wp =
            hout + (size_t)(b * TP_ + t0 + (wgrp << 6) + lrow + 1) * C_;
#pragma unroll
        for (int ni = 0; ni < 8; ++ni) {
          const float v = acc[mi][ni][rq] + bb8[ni];
          const float o = fmaxf(0.f, (v - mu) * rsv * g8[ni] + e8[ni]);
          wp[wnn + (ni << 4) + r15] = __float2bfloat16(o);
        }
      } else {
        float sd = 0.f;
#pragma unroll
        for (int ni = 0; ni < 8; ++ni) {
          const float v = acc[mi][ni][rq] + bb8[ni];
          const float o = fmaxf(0.f, (v - mu) * rsv * g8[ni] + e8[ni]);
          sd += o * wl8[ni];
        }
#pragma unroll
        for (int off = 1; off < 16; off <<= 1) sd += __shfl_xor(sd, off);
        if (r15 == 0)
          scr2[(((wgrp << 6) + lrow) << 2) + wslice] = sd;
      }
    }

  if (MODE == 1) {
    __syncthreads();
    if (wslice == 0 && r15 == 0) {
#pragma unroll
      for (int mi = 0; mi < 4; ++mi)
#pragma unroll
        for (int rq = 0; rq < 4; ++rq) {
          const int lrow = (mi << 4) + (g << 2) + rq;
          const int base2 = ((wgrp << 6) + lrow) << 2;
          const float S = scr2[base2] + scr2[base2 + 1] +
                          scr2[base2 + 2] + scr2[base2 + 3];
          lout[m0 + (wgrp << 6) + lrow] = S + bl[0];
        }
    }
  }
}

// ---------------------------------------------------------------------------
extern "C" void kernel_launch(void* const* d_in, const int* in_sizes, int n_in,
                              void* d_out, int out_size, void* d_ws, size_t ws_size,
                              hipStream_t stream) {
  const float* x     = (const float*)d_in[0];
  const int*   dur   = (const int*)d_in[1];
  const float* W1    = (const float*)d_in[2];
  const float* b1    = (const float*)d_in[3];
  const float* g1    = (const float*)d_in[4];
  const float* beta1 = (const float*)d_in[5];
  const float* W2    = (const float*)d_in[6];
  const float* b2    = (const float*)d_in[7];
  const float* g2    = (const float*)d_in[8];
  const float* beta2 = (const float*)d_in[9];
  const float* Wl    = (const float*)d_in[10];
  const float* bl    = (const float*)d_in[11];

  float* out = (float*)d_out;
  float* res    = out;                              // [B, TOUT, C]
  float* loglen = out + (size_t)B_ * TOUT_ * C_;    // [B, T]

  char* ws = (char*)d_ws;
  __hip_bfloat16* xpad = (__hip_bfloat16*)ws;                       // 8.45 MB
  __hip_bfloat16* hpad = xpad + (size_t)B_ * TP_ * C_;              // 8.45 MB
  __hip_bfloat16* Wt1  = hpad + (size_t)B_ * TP_ * C_;              // 1.57 MB
  __hip_bfloat16* Wt2  = Wt1 + (size_t)H_ * K_;                     // 1.57 MB
  int*   csum = (int*)(Wt2 + (size_t)H_ * K_);                      // 32 KB

  prep_kernel<<<4928, 256, 0, stream>>>(x, W1, dur, xpad, hpad, Wt1, csum);

  // conv1+LN1 (64) || expand units 0..1279 (640) || W2 transpose (384)
  conv_fused_kernel<0><<<1088, 512, 0, stream>>>(
      xpad, Wt1, b1, g1, beta1, nullptr, nullptr, hpad, nullptr,
      x, csum, res, W2, Wt2, 0);

  // conv2+LN2+linear (64) || expand units 1280..2559 (640)
  conv_fused_kernel<1><<<704, 512, 0, stream>>>(
      hpad, Wt2, b2, g2, beta2, Wl, bl, nullptr, loglen,
      x, csum, res, nullptr, nullptr, 1280);
}

// Round 20
// 80.246 us; speedup vs baseline: 1.6048x; 1.6048x over previous
//
#include <hip/hip_runtime.h>
#include <hip/hip_bf16.h>

#define B_    32
#define T_    256
#define C_    512
#define H_    512
#define TOUT_ 2048
#define TP_   258        // padded time length (zero row at t=0 and t=257)
#define K_    1536       // 3 * 512
#define EPS_  1e-5f

typedef __attribute__((ext_vector_type(8))) short bf16x8;
typedef __attribute__((ext_vector_type(4))) float f32x4;

#define GLL16(g, l)                                                        \
  __builtin_amdgcn_global_load_lds(                                        \
      (const __attribute__((address_space(1))) void*)(g),                  \
      (__attribute__((address_space(3))) void*)(l), 16, 0, 0)

// ---------------------------------------------------------------------------
// helpers shared by heterogeneous kernels (operate on a 256-thread sub-tid)
// ---------------------------------------------------------------------------
__device__ __forceinline__ void wt_convert_block(const float* __restrict__ W,
                                                 __hip_bfloat16* __restrict__ Wt,
                                                 int k0, int n0, int tid,
                                                 float* tile /* [32][33] */) {
  const int tx = tid & 31;
  const int ty = tid >> 5;
#pragma unroll
  for (int i = 0; i < 4; ++i)
    tile[(ty * 4 + i) * 33 + tx] = W[(size_t)(k0 + ty * 4 + i) * H_ + n0 + tx];
  __syncthreads();
#pragma unroll
  for (int i = 0; i < 4; ++i)
    Wt[(size_t)(n0 + ty * 4 + i) * K_ + k0 + tx] =
        __float2bfloat16(tile[tx * 33 + ty * 4 + i]);
}

// inclusive scan of one batch's 256 durations -> csum (256-thread block)
__device__ __forceinline__ void csum_block(const int* __restrict__ dur,
                                           int* __restrict__ csum,
                                           int b, int tid, int* wsum) {
  int v = dur[b * T_ + tid];
#pragma unroll
  for (int off = 1; off < 64; off <<= 1) {
    int u = __shfl_up(v, off);
    if ((tid & 63) >= off) v += u;
  }
  if ((tid & 63) == 63) wsum[tid >> 6] = v;
  __syncthreads();
  int base = 0;
#pragma unroll
  for (int j = 0; j < 4; ++j)
    if (j < (tid >> 6)) base += wsum[j];
  csum[b * T_ + tid] = v + base;
}

// copy unit: 16 source rows; read row once, write its d output rows
__device__ __forceinline__ void expand_copy_block(const float* __restrict__ X,
                                                  const int* __restrict__ csum,
                                                  float* __restrict__ res,
                                                  int u, int tid) {
  const int wave = (tid >> 6) & 3, lane = tid & 63;
#pragma unroll
  for (int k = 0; k < 4; ++k) {
    const int sr = u * 16 + wave * 4 + k;    // 0..8191
    const int b = sr >> 8, t = sr & 255;
    const int* cb = csum + b * T_;
    const int c0 = t ? cb[t - 1] : 0;
    const int d  = cb[t] - c0;
    if (d == 0) continue;
    const float* src = X + (size_t)sr * C_;
    const float4 v0 = *(const float4*)(src + lane * 4);
    const float4 v1 = *(const float4*)(src + 256 + lane * 4);
    float* dst = res + ((size_t)b * TOUT_ + c0) * C_;
    for (int j = 0; j < d; ++j) {
      *(float4*)(dst + (size_t)j * C_ + lane * 4)       = v0;
      *(float4*)(dst + (size_t)j * C_ + 256 + lane * 4) = v1;
    }
  }
}

// zero unit: 32 output rows of one batch, zero those >= total
__device__ __forceinline__ void expand_zero_block(const int* __restrict__ csum,
                                                  float* __restrict__ res,
                                                  int z, int tid) {
  const int b  = z >> 6;
  const int t0 = (z & 63) << 5;
  const int total = csum[b * T_ + 255];
  const float4 z4 = make_float4(0.f, 0.f, 0.f, 0.f);
  const int half = (tid >> 7) & 1, c4 = tid & 127;
#pragma unroll
  for (int rr = half; rr < 32; rr += 2) {
    const int r = t0 + rr;
    if (r >= total)
      *(float4*)(res + ((size_t)b * TOUT_ + r) * C_ + c4 * 4) = z4;
  }
}

// ---------------------------------------------------------------------------
// 1) prep (256 threads): cvt_x_pad (0..4127) + cvt W1 (4128..4895) +
//    cvt W2 (4896..5663) + csum (5664..5695)
// ---------------------------------------------------------------------------
__global__ __launch_bounds__(256) void prep_kernel(const float* __restrict__ X,
                                                   const float* __restrict__ W1,
                                                   const float* __restrict__ W2,
                                                   const int* __restrict__ dur,
                                                   __hip_bfloat16* __restrict__ xpad,
                                                   __hip_bfloat16* __restrict__ hpad,
                                                   __hip_bfloat16* __restrict__ Wt1,
                                                   __hip_bfloat16* __restrict__ Wt2,
                                                   int* __restrict__ csum) {
  __shared__ float tile[32 * 33];
  const int tid = threadIdx.x;
  if (blockIdx.x >= 5664) {
    csum_block(dur, csum, blockIdx.x - 5664, tid, (int*)tile);
    return;
  }
  if (blockIdx.x >= 4896) {
    const int id = blockIdx.x - 4896;       // 0..767
    wt_convert_block(W2, Wt2, (id % 48) * 32, (id / 48) * 32, tid, tile);
    return;
  }
  if (blockIdx.x >= 4128) {
    const int id = blockIdx.x - 4128;       // 0..767
    wt_convert_block(W1, Wt1, (id % 48) * 32, (id / 48) * 32, tid, tile);
    return;
  }
  const int row = blockIdx.x * 2 + (tid >> 7);   // 0..8255
  const int b = row / TP_;
  const int t = row - b * TP_;
  const int c = (tid & 127) * 4;
  __hip_bfloat16* dst = xpad + (size_t)row * C_ + c;
  if (t == 0 || t == TP_ - 1) {
    ushort4 zz = make_ushort4(0, 0, 0, 0);
    *(ushort4*)dst = zz;
    *(ushort4*)(hpad + (size_t)row * C_ + c) = zz;
    return;
  }
  const float4 v = *(const float4*)(X + (size_t)(b * T_ + t - 1) * C_ + c);
  union { __hip_bfloat16 h[4]; ushort4 u; } o;
  o.h[0] = __float2bfloat16(v.x);
  o.h[1] = __float2bfloat16(v.y);
  o.h[2] = __float2bfloat16(v.z);
  o.h[3] = __float2bfloat16(v.w);
  *(ushort4*)dst = o.u;
}

// ---------------------------------------------------------------------------
// 2) heterogeneous, 512 threads/block (R17-champion structure):
//    conv GEMM (0..255) || expand (256..895, 2 units/block)
//    conv: 128(M)x128(N), BK=64 (two 32-k slabs), 24 steps, 8 waves of 64x32,
//    2-buf ring (64 KB LDS), counted vmcnt(4), line-coalesced staging
//    (4 lanes/row x 64B line, within-line slot swizzle). Output Y is bf16.
// ---------------------------------------------------------------------------
__global__ __launch_bounds__(512) void conv_expand_kernel(
    const __hip_bfloat16* __restrict__ Apad,   // [32*258, 512]
    const __hip_bfloat16* __restrict__ Wt,     // [512, 1536]
    const float* __restrict__ bias,            // [512]
    __hip_bfloat16* __restrict__ Y,            // [8192, 512] bf16
    const float* __restrict__ X,               // f32 input (for expand)
    const int* __restrict__ csum,
    float* __restrict__ res,
    int ex_base) {
  __shared__ __hip_bfloat16 smA[2][2][4096];   // [buf][slab][row128*32] = 32 KB
  __shared__ __hip_bfloat16 smB[2][2][4096];   // [buf][slab][row128*32] = 32 KB

  const int tid = threadIdx.x;                 // 0..511

  if (blockIdx.x >= 256) {                     // expand: 2 units/block
    const int u = ex_base + (blockIdx.x - 256) * 2 + (tid >> 8);
    const int st = tid & 255;
    if (u < 512) expand_copy_block(X, csum, res, u, st);
    else         expand_zero_block(csum, res, u - 512, st);
    return;
  }

  // ---- conv GEMM path: 128(M) x 128(N), 8 waves of 64x32 ----
  const int lane = tid & 63;
  const int wid  = tid >> 6;                   // 0..7
  const int cid  = blockIdx.x;
  const int n0 = (cid & 3) << 7;               // 0,128,256,384
  const int m0 = (cid >> 2) << 7;              // 0..8064
  const int b  = m0 >> 8;
  const int t0 = m0 & 255;                     // 0 or 128
  const int wm = (wid >> 2) << 6;              // 0 / 64
  const int wn = (wid & 3) << 5;               // 0,32,64,96

  // staging coords: 4 lanes/row, 16B each, within-line slot swizzle
  const int rowS = tid >> 2;                   // 0..127
  const int gsw  = ((tid & 3) + rowS) & 3;
  const __hip_bfloat16* arowA = Apad + (size_t)(b * TP_ + t0 + rowS) * C_ + (gsw << 3);
  const __hip_bfloat16* browB = Wt + (size_t)(n0 + rowS) * K_ + (gsw << 3);

  f32x4 acc[4][2] = {};

  // BK=64 never straddles a conv window (512 % 64 == 0); 4 GLL16/thread
  auto stage = [&](int buf, int k0) {
    const int kw = k0 >> 9;                    // conv window 0..2
    const int c0 = k0 & 511;
    const __hip_bfloat16* a0 = arowA + kw * C_ + c0;
    GLL16(a0,           &smA[buf][0][tid << 3]);
    GLL16(a0 + 32,      &smA[buf][1][tid << 3]);
    GLL16(browB + k0,      &smB[buf][0][tid << 3]);
    GLL16(browB + k0 + 32, &smB[buf][1][tid << 3]);
  };

  auto compute = [&](int buf) {
    const int g   = lane >> 4;
    const int r15 = lane & 15;
    const int sa  = ((g - r15) & 3) << 3;      // swizzled slot offset (elems)
#pragma unroll
    for (int sl = 0; sl < 2; ++sl) {
      const __hip_bfloat16* As = smA[buf][sl];
      const __hip_bfloat16* Bs = smB[buf][sl];
      bf16x8 aF[4], bF[2];
#pragma unroll
      for (int i = 0; i < 4; ++i)
        aF[i] = *(const bf16x8*)(As + ((wm + (i << 4) + r15) << 5) + sa);
#pragma unroll
      for (int i = 0; i < 2; ++i)
        bF[i] = *(const bf16x8*)(Bs + ((wn + (i << 4) + r15) << 5) + sa);
#pragma unroll
      for (int mi = 0; mi < 4; ++mi)
#pragma unroll
        for (int ni = 0; ni < 2; ++ni)
          acc[mi][ni] = __builtin_amdgcn_mfma_f32_16x16x32_bf16(
              aF[mi], bF[ni], acc[mi][ni], 0, 0, 0);
    }
  };

  // prologue: clean baseline, prefetch 2 tiles (8 vmem/wave in flight)
  asm volatile("s_waitcnt vmcnt(0)" ::: "memory");
  stage(0, 0);
  stage(1, 64);

  // main loop: compute tiles 0..21, stage tiles 2..23 (tile t -> buf t&1)
  for (int s = 0; s < 22; ++s) {
    asm volatile("s_waitcnt vmcnt(4)" ::: "memory");   // oldest tile's 4 done
    __builtin_amdgcn_sched_barrier(0);
    __builtin_amdgcn_s_barrier();
    compute(s & 1);
    asm volatile("s_waitcnt lgkmcnt(0)" ::: "memory");
    __builtin_amdgcn_s_barrier();
    stage(s & 1, (s + 2) << 6);
  }
  // tail: tiles 22 (buf0), 23 (buf1) — drain 4 -> 0
  asm volatile("s_waitcnt vmcnt(4)" ::: "memory");
  __builtin_amdgcn_sched_barrier(0);
  __builtin_amdgcn_s_barrier();
  compute(0);
  asm volatile("s_waitcnt vmcnt(0)" ::: "memory");
  __builtin_amdgcn_sched_barrier(0);
  __builtin_amdgcn_s_barrier();
  compute(1);

  // epilogue: C/D layout col = lane&15 (n), row = (lane>>4)*4 + reg (m)
  const int cn_base = n0 + wn + (lane & 15);
  const int rm_base = m0 + wm + ((lane >> 4) << 2);
#pragma unroll
  for (int ni = 0; ni < 2; ++ni) {
    const int cn = cn_base + (ni << 4);
    const float bb = bias[cn];
#pragma unroll
    for (int mi = 0; mi < 4; ++mi) {
#pragma unroll
      for (int rq = 0; rq < 4; ++rq) {
        const int rm = rm_base + (mi << 4) + rq;
        Y[(size_t)rm * H_ + cn] = __float2bfloat16(acc[mi][ni][rq] + bb);
      }
    }
  }
}

// ---------------------------------------------------------------------------
// 3) LayerNorm + ReLU: bf16 in -> bf16 out written into padded layout
// ---------------------------------------------------------------------------
__global__ __launch_bounds__(256) void ln_relu_pad_kernel(
    const __hip_bfloat16* __restrict__ in,
    const float* __restrict__ g,
    const float* __restrict__ beta,
    __hip_bfloat16* __restrict__ outpad) {
  const int wave = threadIdx.x >> 6;
  const int lane = threadIdx.x & 63;
  const int row  = blockIdx.x * 4 + wave;   // 0..8191

  const bf16x8 hv = *(const bf16x8*)(in + (size_t)row * H_ + lane * 8);
  const __hip_bfloat16* hh = (const __hip_bfloat16*)&hv;
  float f[8];
#pragma unroll
  for (int j = 0; j < 8; ++j) f[j] = __bfloat162float(hh[j]);

  float s = 0.f, q = 0.f;
#pragma unroll
  for (int j = 0; j < 8; ++j) { s += f[j]; q += f[j] * f[j]; }
#pragma unroll
  for (int off = 32; off; off >>= 1) {
    s += __shfl_xor(s, off);
    q += __shfl_xor(q, off);
  }
  const float mu  = s * (1.0f / 512.0f);
  const float var = q * (1.0f / 512.0f) - mu * mu;
  const float rs  = rsqrtf(var + EPS_);

  const float4 g0 = *(const float4*)(g + lane * 8);
  const float4 g1 = *(const float4*)(g + lane * 8 + 4);
  const float4 e0 = *(const float4*)(beta + lane * 8);
  const float4 e1 = *(const float4*)(beta + lane * 8 + 4);
  const float gg[8] = {g0.x, g0.y, g0.z, g0.w, g1.x, g1.y, g1.z, g1.w};
  const float ee[8] = {e0.x, e0.y, e0.z, e0.w, e1.x, e1.y, e1.z, e1.w};

  union { __hip_bfloat16 h[8]; bf16x8 v; } o;
#pragma unroll
  for (int j = 0; j < 8; ++j)
    o.h[j] = __float2bfloat16(fmaxf(0.f, (f[j] - mu) * rs * gg[j] + ee[j]));

  const int bq = row >> 8, t = row & 255;
  *(bf16x8*)(outpad + (size_t)(bq * TP_ + t + 1) * H_ + lane * 8) = o.v;
}

// ---------------------------------------------------------------------------
// 4) LayerNorm + ReLU + linear head fused (bf16 in)
// ---------------------------------------------------------------------------
__global__ __launch_bounds__(256) void ln_relu_linear_kernel(
    const __hip_bfloat16* __restrict__ in,
    const float* __restrict__ g,
    const float* __restrict__ beta,
    const float* __restrict__ Wl,
    const float* __restrict__ bl,
    float* __restrict__ out) {
  const int wave = threadIdx.x >> 6;
  const int lane = threadIdx.x & 63;
  const int row  = blockIdx.x * 4 + wave;

  const bf16x8 hv = *(const bf16x8*)(in + (size_t)row * H_ + lane * 8);
  const __hip_bfloat16* hh = (const __hip_bfloat16*)&hv;
  float f[8];
#pragma unroll
  for (int j = 0; j < 8; ++j) f[j] = __bfloat162float(hh[j]);

  float s = 0.f, q = 0.f;
#pragma unroll
  for (int j = 0; j < 8; ++j) { s += f[j]; q += f[j] * f[j]; }
#pragma unroll
  for (int off = 32; off; off >>= 1) {
    s += __shfl_xor(s, off);
    q += __shfl_xor(q, off);
  }
  const float mu  = s * (1.0f / 512.0f);
  const float var = q * (1.0f / 512.0f) - mu * mu;
  const float rs  = rsqrtf(var + EPS_);

  const float4 g0 = *(const float4*)(g + lane * 8);
  const float4 g1 = *(const float4*)(g + lane * 8 + 4);
  const float4 e0 = *(const float4*)(beta + lane * 8);
  const float4 e1 = *(const float4*)(beta + lane * 8 + 4);
  const float4 w0 = *(const float4*)(Wl + lane * 8);
  const float4 w1 = *(const float4*)(Wl + lane * 8 + 4);
  const float gg[8] = {g0.x, g0.y, g0.z, g0.w, g1.x, g1.y, g1.z, g1.w};
  const float ee[8] = {e0.x, e0.y, e0.z, e0.w, e1.x, e1.y, e1.z, e1.w};
  const float ww[8] = {w0.x, w0.y, w0.z, w0.w, w1.x, w1.y, w1.z, w1.w};

  float sd = 0.f;
#pragma unroll
  for (int j = 0; j < 8; ++j)
    sd += fmaxf(0.f, (f[j] - mu) * rs * gg[j] + ee[j]) * ww[j];
#pragma unroll
  for (int off = 32; off; off >>= 1) sd += __shfl_xor(sd, off);

  if (lane == 0) out[row] = sd + bl[0];
}

// ---------------------------------------------------------------------------
extern "C" void kernel_launch(void* const* d_in, const int* in_sizes, int n_in,
                              void* d_out, int out_size, void* d_ws, size_t ws_size,
                              hipStream_t stream) {
  const float* x     = (const float*)d_in[0];
  const int*   dur   = (const int*)d_in[1];
  const float* W1    = (const float*)d_in[2];
  const float* b1    = (const float*)d_in[3];
  const float* g1    = (const float*)d_in[4];
  const float* beta1 = (const float*)d_in[5];
  const float* W2    = (const float*)d_in[6];
  const float* b2    = (const float*)d_in[7];
  const float* g2    = (const float*)d_in[8];
  const float* beta2 = (const float*)d_in[9];
  const float* Wl    = (const float*)d_in[10];
  const float* bl    = (const float*)d_in[11];

  float* out = (float*)d_out;
  float* res    = out;                              // [B, TOUT, C]
  float* loglen = out + (size_t)B_ * TOUT_ * C_;    // [B, T]

  char* ws = (char*)d_ws;
  __hip_bfloat16* xpad = (__hip_bfloat16*)ws;                       // 8.45 MB
  __hip_bfloat16* hpad = xpad + (size_t)B_ * TP_ * C_;              // 8.45 MB
  __hip_bfloat16* Wt1  = hpad + (size_t)B_ * TP_ * C_;              // 1.57 MB
  __hip_bfloat16* Wt2  = Wt1 + (size_t)H_ * K_;                     // 1.57 MB
  __hip_bfloat16* tmp  = Wt2 + (size_t)H_ * K_;                     // 8.39 MB bf16
  int*   csum = (int*)(tmp + (size_t)B_ * T_ * H_);                 // 32 KB

  prep_kernel<<<5696, 256, 0, stream>>>(x, W1, W2, dur, xpad, hpad,
                                        Wt1, Wt2, csum);

  // conv1 (256) || expand units 0..1279 (640 blocks)
  conv_expand_kernel<<<896, 512, 0, stream>>>(xpad, Wt1, b1, tmp,
                                              x, csum, res, 0);
  ln_relu_pad_kernel<<<B_ * T_ / 4, 256, 0, stream>>>(tmp, g1, beta1, hpad);

  // conv2 (256) || expand units 1280..2559 (640 blocks)
  conv_expand_kernel<<<896, 512, 0, stream>>>(hpad, Wt2, b2, tmp,
                                              x, csum, res, 1280);
  ln_relu_linear_kernel<<<B_ * T_ / 4, 256, 0, stream>>>(tmp, g2, beta2, Wl, bl, loglen);
}

// Round 21
// 72.199 us; speedup vs baseline: 1.7836x; 1.1115x over previous
//
#include <hip/hip_runtime.h>
#include <hip/hip_bf16.h>

#define B_    32
#define T_    256
#define C_    512
#define H_    512
#define TOUT_ 2048
#define TP_   258        // padded time length (zero row at t=0 and t=257)
#define K_    1536       // 3 * 512
#define EPS_  1e-5f

typedef __attribute__((ext_vector_type(8))) short bf16x8;
typedef __attribute__((ext_vector_type(4))) float f32x4;

#define GLL16(g, l)                                                        \
  __builtin_amdgcn_global_load_lds(                                        \
      (const __attribute__((address_space(1))) void*)(g),                  \
      (__attribute__((address_space(3))) void*)(l), 16, 0, 0)

// ---------------------------------------------------------------------------
// helpers shared by heterogeneous kernels (operate on a 256-thread sub-tid)
// ---------------------------------------------------------------------------
__device__ __forceinline__ void wt_convert_block(const float* __restrict__ W,
                                                 __hip_bfloat16* __restrict__ Wt,
                                                 int k0, int n0, int tid,
                                                 float* tile /* [32][33] */) {
  const int tx = tid & 31;
  const int ty = tid >> 5;
#pragma unroll
  for (int i = 0; i < 4; ++i)
    tile[(ty * 4 + i) * 33 + tx] = W[(size_t)(k0 + ty * 4 + i) * H_ + n0 + tx];
  __syncthreads();
#pragma unroll
  for (int i = 0; i < 4; ++i)
    Wt[(size_t)(n0 + ty * 4 + i) * K_ + k0 + tx] =
        __float2bfloat16(tile[tx * 33 + ty * 4 + i]);
}

// inclusive scan of one batch's 256 durations -> csum (256-thread block)
__device__ __forceinline__ void csum_block(const int* __restrict__ dur,
                                           int* __restrict__ csum,
                                           int b, int tid, int* wsum) {
  int v = dur[b * T_ + tid];
#pragma unroll
  for (int off = 1; off < 64; off <<= 1) {
    int u = __shfl_up(v, off);
    if ((tid & 63) >= off) v += u;
  }
  if ((tid & 63) == 63) wsum[tid >> 6] = v;
  __syncthreads();
  int base = 0;
#pragma unroll
  for (int j = 0; j < 4; ++j)
    if (j < (tid >> 6)) base += wsum[j];
  csum[b * T_ + tid] = v + base;
}

// copy unit: 16 source rows; read row once, write its d output rows
__device__ __forceinline__ void expand_copy_block(const float* __restrict__ X,
                                                  const int* __restrict__ csum,
                                                  float* __restrict__ res,
                                                  int u, int tid) {
  const int wave = (tid >> 6) & 3, lane = tid & 63;
#pragma unroll
  for (int k = 0; k < 4; ++k) {
    const int sr = u * 16 + wave * 4 + k;    // 0..8191
    const int b = sr >> 8, t = sr & 255;
    const int* cb = csum + b * T_;
    const int c0 = t ? cb[t - 1] : 0;
    const int d  = cb[t] - c0;
    if (d == 0) continue;
    const float* src = X + (size_t)sr * C_;
    const float4 v0 = *(const float4*)(src + lane * 4);
    const float4 v1 = *(const float4*)(src + 256 + lane * 4);
    float* dst = res + ((size_t)b * TOUT_ + c0) * C_;
    for (int j = 0; j < d; ++j) {
      *(float4*)(dst + (size_t)j * C_ + lane * 4)       = v0;
      *(float4*)(dst + (size_t)j * C_ + 256 + lane * 4) = v1;
    }
  }
}

// zero unit: 32 output rows of one batch, zero those >= total
__device__ __forceinline__ void expand_zero_block(const int* __restrict__ csum,
                                                  float* __restrict__ res,
                                                  int z, int tid) {
  const int b  = z >> 6;
  const int t0 = (z & 63) << 5;
  const int total = csum[b * T_ + 255];
  const float4 z4 = make_float4(0.f, 0.f, 0.f, 0.f);
  const int half = (tid >> 7) & 1, c4 = tid & 127;
#pragma unroll
  for (int rr = half; rr < 32; rr += 2) {
    const int r = t0 + rr;
    if (r >= total)
      *(float4*)(res + ((size_t)b * TOUT_ + r) * C_ + c4 * 4) = z4;
  }
}

// ---------------------------------------------------------------------------
// 1) prep (256 threads): cvt_x_pad (0..4127) + cvt W1 (4128..4895) +
//    cvt W2 (4896..5663) + csum (5664..5695)
// ---------------------------------------------------------------------------
__global__ __launch_bounds__(256) void prep_kernel(const float* __restrict__ X,
                                                   const float* __restrict__ W1,
                                                   const float* __restrict__ W2,
                                                   const int* __restrict__ dur,
                                                   __hip_bfloat16* __restrict__ xpad,
                                                   __hip_bfloat16* __restrict__ hpad,
                                                   __hip_bfloat16* __restrict__ Wt1,
                                                   __hip_bfloat16* __restrict__ Wt2,
                                                   int* __restrict__ csum) {
  __shared__ float tile[32 * 33];
  const int tid = threadIdx.x;
  if (blockIdx.x >= 5664) {
    csum_block(dur, csum, blockIdx.x - 5664, tid, (int*)tile);
    return;
  }
  if (blockIdx.x >= 4896) {
    const int id = blockIdx.x - 4896;       // 0..767
    wt_convert_block(W2, Wt2, (id % 48) * 32, (id / 48) * 32, tid, tile);
    return;
  }
  if (blockIdx.x >= 4128) {
    const int id = blockIdx.x - 4128;       // 0..767
    wt_convert_block(W1, Wt1, (id % 48) * 32, (id / 48) * 32, tid, tile);
    return;
  }
  const int row = blockIdx.x * 2 + (tid >> 7);   // 0..8255
  const int b = row / TP_;
  const int t = row - b * TP_;
  const int c = (tid & 127) * 4;
  __hip_bfloat16* dst = xpad + (size_t)row * C_ + c;
  if (t == 0 || t == TP_ - 1) {
    ushort4 zz = make_ushort4(0, 0, 0, 0);
    *(ushort4*)dst = zz;
    *(ushort4*)(hpad + (size_t)row * C_ + c) = zz;
    return;
  }
  const float4 v = *(const float4*)(X + (size_t)(b * T_ + t - 1) * C_ + c);
  union { __hip_bfloat16 h[4]; ushort4 u; } o;
  o.h[0] = __float2bfloat16(v.x);
  o.h[1] = __float2bfloat16(v.y);
  o.h[2] = __float2bfloat16(v.z);
  o.h[3] = __float2bfloat16(v.w);
  *(ushort4*)dst = o.u;
}

// ---------------------------------------------------------------------------
// 2) heterogeneous, 512 threads/block (R17-champion structure):
//    conv GEMM (0..255) || expand (256..895, 2 units/block)
//    conv: 128(M)x128(N), BK=64 (two 32-k slabs), 24 steps, 8 waves of 64x32,
//    2-buf ring (64 KB LDS), counted vmcnt(4), line-coalesced staging.
//    XCD-aware tile assignment (T1): blocks land on XCD ~ cid%8; give each
//    XCD a contiguous 8-m-tile x 4-n-tile band so its A working set (1 MB)
//    + Wt (1.5 MB) fit the 4 MB per-XCD L2.  Output Y is bf16.
// ---------------------------------------------------------------------------
__global__ __launch_bounds__(512) void conv_expand_kernel(
    const __hip_bfloat16* __restrict__ Apad,   // [32*258, 512]
    const __hip_bfloat16* __restrict__ Wt,     // [512, 1536]
    const float* __restrict__ bias,            // [512]
    __hip_bfloat16* __restrict__ Y,            // [8192, 512] bf16
    const float* __restrict__ X,               // f32 input (for expand)
    const int* __restrict__ csum,
    float* __restrict__ res,
    int ex_base) {
  __shared__ __hip_bfloat16 smA[2][2][4096];   // [buf][slab][row128*32] = 32 KB
  __shared__ __hip_bfloat16 smB[2][2][4096];   // [buf][slab][row128*32] = 32 KB

  const int tid = threadIdx.x;                 // 0..511

  if (blockIdx.x >= 256) {                     // expand: 2 units/block
    const int u = ex_base + (blockIdx.x - 256) * 2 + (tid >> 8);
    const int st = tid & 255;
    if (u < 512) expand_copy_block(X, csum, res, u, st);
    else         expand_zero_block(csum, res, u - 512, st);
    return;
  }

  // ---- conv GEMM path: 128(M) x 128(N), 8 waves of 64x32 ----
  const int lane = tid & 63;
  const int wid  = tid >> 6;                   // 0..7
  // XCD-aware remap (bijective on [0,256)): xcd = cid&7 keeps its band
  const int cid = blockIdx.x;
  const int xcd = cid & 7;
  const int idx = cid >> 3;                    // 0..31
  const int mt  = (xcd << 3) + (idx >> 2);     // 0..63
  const int nt  = idx & 3;                     // 0..3
  const int n0 = nt << 7;                      // 0,128,256,384
  const int m0 = mt << 7;                      // 0..8064
  const int b  = m0 >> 8;
  const int t0 = m0 & 255;                     // 0 or 128
  const int wm = (wid >> 2) << 6;              // 0 / 64
  const int wn = (wid & 3) << 5;               // 0,32,64,96

  // staging coords: 4 lanes/row, 16B each, within-line slot swizzle
  const int rowS = tid >> 2;                   // 0..127
  const int gsw  = ((tid & 3) + rowS) & 3;
  const __hip_bfloat16* arowA = Apad + (size_t)(b * TP_ + t0 + rowS) * C_ + (gsw << 3);
  const __hip_bfloat16* browB = Wt + (size_t)(n0 + rowS) * K_ + (gsw << 3);

  f32x4 acc[4][2] = {};

  // BK=64 never straddles a conv window (512 % 64 == 0); 4 GLL16/thread
  auto stage = [&](int buf, int k0) {
    const int kw = k0 >> 9;                    // conv window 0..2
    const int c0 = k0 & 511;
    const __hip_bfloat16* a0 = arowA + kw * C_ + c0;
    GLL16(a0,           &smA[buf][0][tid << 3]);
    GLL16(a0 + 32,      &smA[buf][1][tid << 3]);
    GLL16(browB + k0,      &smB[buf][0][tid << 3]);
    GLL16(browB + k0 + 32, &smB[buf][1][tid << 3]);
  };

  auto compute = [&](int buf) {
    const int g   = lane >> 4;
    const int r15 = lane & 15;
    const int sa  = ((g - r15) & 3) << 3;      // swizzled slot offset (elems)
#pragma unroll
    for (int sl = 0; sl < 2; ++sl) {
      const __hip_bfloat16* As = smA[buf][sl];
      const __hip_bfloat16* Bs = smB[buf][sl];
      bf16x8 aF[4], bF[2];
#pragma unroll
      for (int i = 0; i < 4; ++i)
        aF[i] = *(const bf16x8*)(As + ((wm + (i << 4) + r15) << 5) + sa);
#pragma unroll
      for (int i = 0; i < 2; ++i)
        bF[i] = *(const bf16x8*)(Bs + ((wn + (i << 4) + r15) << 5) + sa);
#pragma unroll
      for (int mi = 0; mi < 4; ++mi)
#pragma unroll
        for (int ni = 0; ni < 2; ++ni)
          acc[mi][ni] = __builtin_amdgcn_mfma_f32_16x16x32_bf16(
              aF[mi], bF[ni], acc[mi][ni], 0, 0, 0);
    }
  };

  // prologue: clean baseline, prefetch 2 tiles (8 vmem/wave in flight)
  asm volatile("s_waitcnt vmcnt(0)" ::: "memory");
  stage(0, 0);
  stage(1, 64);

  // main loop: compute tiles 0..21, stage tiles 2..23 (tile t -> buf t&1)
  for (int s = 0; s < 22; ++s) {
    asm volatile("s_waitcnt vmcnt(4)" ::: "memory");   // oldest tile's 4 done
    __builtin_amdgcn_sched_barrier(0);
    __builtin_amdgcn_s_barrier();
    compute(s & 1);
    asm volatile("s_waitcnt lgkmcnt(0)" ::: "memory");
    __builtin_amdgcn_s_barrier();
    stage(s & 1, (s + 2) << 6);
  }
  // tail: tiles 22 (buf0), 23 (buf1) — drain 4 -> 0
  asm volatile("s_waitcnt vmcnt(4)" ::: "memory");
  __builtin_amdgcn_sched_barrier(0);
  __builtin_amdgcn_s_barrier();
  compute(0);
  asm volatile("s_waitcnt vmcnt(0)" ::: "memory");
  __builtin_amdgcn_sched_barrier(0);
  __builtin_amdgcn_s_barrier();
  compute(1);

  // epilogue: C/D layout col = lane&15 (n), row = (lane>>4)*4 + reg (m)
  const int cn_base = n0 + wn + (lane & 15);
  const int rm_base = m0 + wm + ((lane >> 4) << 2);
#pragma unroll
  for (int ni = 0; ni < 2; ++ni) {
    const int cn = cn_base + (ni << 4);
    const float bb = bias[cn];
#pragma unroll
    for (int mi = 0; mi < 4; ++mi) {
#pragma unroll
      for (int rq = 0; rq < 4; ++rq) {
        const int rm = rm_base + (mi << 4) + rq;
        Y[(size_t)rm * H_ + cn] = __float2bfloat16(acc[mi][ni][rq] + bb);
      }
    }
  }
}

// ---------------------------------------------------------------------------
// 3) LayerNorm + ReLU: bf16 in -> bf16 out written into padded layout
// ---------------------------------------------------------------------------
__global__ __launch_bounds__(256) void ln_relu_pad_kernel(
    const __hip_bfloat16* __restrict__ in,
    const float* __restrict__ g,
    const float* __restrict__ beta,
    __hip_bfloat16* __restrict__ outpad) {
  const int wave = threadIdx.x >> 6;
  const int lane = threadIdx.x & 63;
  const int row  = blockIdx.x * 4 + wave;   // 0..8191

  const bf16x8 hv = *(const bf16x8*)(in + (size_t)row * H_ + lane * 8);
  const __hip_bfloat16* hh = (const __hip_bfloat16*)&hv;
  float f[8];
#pragma unroll
  for (int j = 0; j < 8; ++j) f[j] = __bfloat162float(hh[j]);

  float s = 0.f, q = 0.f;
#pragma unroll
  for (int j = 0; j < 8; ++j) { s += f[j]; q += f[j] * f[j]; }
#pragma unroll
  for (int off = 32; off; off >>= 1) {
    s += __shfl_xor(s, off);
    q += __shfl_xor(q, off);
  }
  const float mu  = s * (1.0f / 512.0f);
  const float var = q * (1.0f / 512.0f) - mu * mu;
  const float rs  = rsqrtf(var + EPS_);

  const float4 g0 = *(const float4*)(g + lane * 8);
  const float4 g1 = *(const float4*)(g + lane * 8 + 4);
  const float4 e0 = *(const float4*)(beta + lane * 8);
  const float4 e1 = *(const float4*)(beta + lane * 8 + 4);
  const float gg[8] = {g0.x, g0.y, g0.z, g0.w, g1.x, g1.y, g1.z, g1.w};
  const float ee[8] = {e0.x, e0.y, e0.z, e0.w, e1.x, e1.y, e1.z, e1.w};

  union { __hip_bfloat16 h[8]; bf16x8 v; } o;
#pragma unroll
  for (int j = 0; j < 8; ++j)
    o.h[j] = __float2bfloat16(fmaxf(0.f, (f[j] - mu) * rs * gg[j] + ee[j]));

  const int bq = row >> 8, t = row & 255;
  *(bf16x8*)(outpad + (size_t)(bq * TP_ + t + 1) * H_ + lane * 8) = o.v;
}

// ---------------------------------------------------------------------------
// 4) LayerNorm + ReLU + linear head fused (bf16 in)
// ---------------------------------------------------------------------------
__global__ __launch_bounds__(256) void ln_relu_linear_kernel(
    const __hip_bfloat16* __restrict__ in,
    const float* __restrict__ g,
    const float* __restrict__ beta,
    const float* __restrict__ Wl,
    const float* __restrict__ bl,
    float* __restrict__ out) {
  const int wave = threadIdx.x >> 6;
  const int lane = threadIdx.x & 63;
  const int row  = blockIdx.x * 4 + wave;

  const bf16x8 hv = *(const bf16x8*)(in + (size_t)row * H_ + lane * 8);
  const __hip_bfloat16* hh = (const __hip_bfloat16*)&hv;
  float f[8];
#pragma unroll
  for (int j = 0; j < 8; ++j) f[j] = __bfloat162float(hh[j]);

  float s = 0.f, q = 0.f;
#pragma unroll
  for (int j = 0; j < 8; ++j) { s += f[j]; q += f[j] * f[j]; }
#pragma unroll
  for (int off = 32; off; off >>= 1) {
    s += __shfl_xor(s, off);
    q += __shfl_xor(q, off);
  }
  const float mu  = s * (1.0f / 512.0f);
  const float var = q * (1.0f / 512.0f) - mu * mu;
  const float rs  = rsqrtf(var + EPS_);

  const float4 g0 = *(const float4*)(g + lane * 8);
  const float4 g1 = *(const float4*)(g + lane * 8 + 4);
  const float4 e0 = *(const float4*)(beta + lane * 8);
  const float4 e1 = *(const float4*)(beta + lane * 8 + 4);
  const float4 w0 = *(const float4*)(Wl + lane * 8);
  const float4 w1 = *(const float4*)(Wl + lane * 8 + 4);
  const float gg[8] = {g0.x, g0.y, g0.z, g0.w, g1.x, g1.y, g1.z, g1.w};
  const float ee[8] = {e0.x, e0.y, e0.z, e0.w, e1.x, e1.y, e1.z, e1.w};
  const float ww[8] = {w0.x, w0.y, w0.z, w0.w, w1.x, w1.y, w1.z, w1.w};

  float sd = 0.f;
#pragma unroll
  for (int j = 0; j < 8; ++j)
    sd += fmaxf(0.f, (f[j] - mu) * rs * gg[j] + ee[j]) * ww[j];
#pragma unroll
  for (int off = 32; off; off >>= 1) sd += __shfl_xor(sd, off);

  if (lane == 0) out[row] = sd + bl[0];
}

// ---------------------------------------------------------------------------
extern "C" void kernel_launch(void* const* d_in, const int* in_sizes, int n_in,
                              void* d_out, int out_size, void* d_ws, size_t ws_size,
                              hipStream_t stream) {
  const float* x     = (const float*)d_in[0];
  const int*   dur   = (const int*)d_in[1];
  const float* W1    = (const float*)d_in[2];
  const float* b1    = (const float*)d_in[3];
  const float* g1    = (const float*)d_in[4];
  const float* beta1 = (const float*)d_in[5];
  const float* W2    = (const float*)d_in[6];
  const float* b2    = (const float*)d_in[7];
  const float* g2    = (const float*)d_in[8];
  const float* beta2 = (const float*)d_in[9];
  const float* Wl    = (const float*)d_in[10];
  const float* bl    = (const float*)d_in[11];

  float* out = (float*)d_out;
  float* res    = out;                              // [B, TOUT, C]
  float* loglen = out + (size_t)B_ * TOUT_ * C_;    // [B, T]

  char* ws = (char*)d_ws;
  __hip_bfloat16* xpad = (__hip_bfloat16*)ws;                       // 8.45 MB
  __hip_bfloat16* hpad = xpad + (size_t)B_ * TP_ * C_;              // 8.45 MB
  __hip_bfloat16* Wt1  = hpad + (size_t)B_ * TP_ * C_;              // 1.57 MB
  __hip_bfloat16* Wt2  = Wt1 + (size_t)H_ * K_;                     // 1.57 MB
  __hip_bfloat16* tmp  = Wt2 + (size_t)H_ * K_;                     // 8.39 MB bf16
  int*   csum = (int*)(tmp + (size_t)B_ * T_ * H_);                 // 32 KB

  prep_kernel<<<5696, 256, 0, stream>>>(x, W1, W2, dur, xpad, hpad,
                                        Wt1, Wt2, csum);

  // conv1 (256) || expand units 0..1279 (640 blocks)
  conv_expand_kernel<<<896, 512, 0, stream>>>(xpad, Wt1, b1, tmp,
                                              x, csum, res, 0);
  ln_relu_pad_kernel<<<B_ * T_ / 4, 256, 0, stream>>>(tmp, g1, beta1, hpad);

  // conv2 (256) || expand units 1280..2559 (640 blocks)
  conv_expand_kernel<<<896, 512, 0, stream>>>(hpad, Wt2, b2, tmp,
                                              x, csum, res, 1280);
  ln_relu_linear_kernel<<<B_ * T_ / 4, 256, 0, stream>>>(tmp, g2, beta2, Wl, bl, loglen);
}

// Round 22
// 69.178 us; speedup vs baseline: 1.8615x; 1.0437x over previous
//
#include <hip/hip_runtime.h>
#include <hip/hip_bf16.h>

#define B_    32
#define T_    256
#define C_    512
#define H_    512
#define TOUT_ 2048
#define TP_   258        // padded time length (zero row at t=0 and t=257)
#define K_    1536       // 3 * 512
#define EPS_  1e-5f

typedef __attribute__((ext_vector_type(8))) short bf16x8;
typedef __attribute__((ext_vector_type(4))) float f32x4;

#define GLL16(g, l)                                                        \
  __builtin_amdgcn_global_load_lds(                                        \
      (const __attribute__((address_space(1))) void*)(g),                  \
      (__attribute__((address_space(3))) void*)(l), 16, 0, 0)

// ---------------------------------------------------------------------------
// helpers shared by heterogeneous kernels (operate on a 256-thread sub-tid)
// ---------------------------------------------------------------------------
__device__ __forceinline__ void wt_convert_block(const float* __restrict__ W,
                                                 __hip_bfloat16* __restrict__ Wt,
                                                 int k0, int n0, int tid,
                                                 float* tile /* [32][33] */) {
  const int tx = tid & 31;
  const int ty = tid >> 5;
#pragma unroll
  for (int i = 0; i < 4; ++i)
    tile[(ty * 4 + i) * 33 + tx] = W[(size_t)(k0 + ty * 4 + i) * H_ + n0 + tx];
  __syncthreads();
#pragma unroll
  for (int i = 0; i < 4; ++i)
    Wt[(size_t)(n0 + ty * 4 + i) * K_ + k0 + tx] =
        __float2bfloat16(tile[tx * 33 + ty * 4 + i]);
}

// inclusive scan of one batch's 256 durations -> csum (256-thread block)
__device__ __forceinline__ void csum_block(const int* __restrict__ dur,
                                           int* __restrict__ csum,
                                           int b, int tid, int* wsum) {
  int v = dur[b * T_ + tid];
#pragma unroll
  for (int off = 1; off < 64; off <<= 1) {
    int u = __shfl_up(v, off);
    if ((tid & 63) >= off) v += u;
  }
  if ((tid & 63) == 63) wsum[tid >> 6] = v;
  __syncthreads();
  int base = 0;
#pragma unroll
  for (int j = 0; j < 4; ++j)
    if (j < (tid >> 6)) base += wsum[j];
  csum[b * T_ + tid] = v + base;
}

// copy unit: 16 source rows; read row once, write its d output rows
__device__ __forceinline__ void expand_copy_block(const float* __restrict__ X,
                                                  const int* __restrict__ csum,
                                                  float* __restrict__ res,
                                                  int u, int tid) {
  const int wave = (tid >> 6) & 3, lane = tid & 63;
#pragma unroll
  for (int k = 0; k < 4; ++k) {
    const int sr = u * 16 + wave * 4 + k;    // 0..8191
    const int b = sr >> 8, t = sr & 255;
    const int* cb = csum + b * T_;
    const int c0 = t ? cb[t - 1] : 0;
    const int d  = cb[t] - c0;
    if (d == 0) continue;
    const float* src = X + (size_t)sr * C_;
    const float4 v0 = *(const float4*)(src + lane * 4);
    const float4 v1 = *(const float4*)(src + 256 + lane * 4);
    float* dst = res + ((size_t)b * TOUT_ + c0) * C_;
    for (int j = 0; j < d; ++j) {
      *(float4*)(dst + (size_t)j * C_ + lane * 4)       = v0;
      *(float4*)(dst + (size_t)j * C_ + 256 + lane * 4) = v1;
    }
  }
}

// zero unit: 32 output rows of one batch, zero those >= total
__device__ __forceinline__ void expand_zero_block(const int* __restrict__ csum,
                                                  float* __restrict__ res,
                                                  int z, int tid) {
  const int b  = z >> 6;
  const int t0 = (z & 63) << 5;
  const int total = csum[b * T_ + 255];
  const float4 z4 = make_float4(0.f, 0.f, 0.f, 0.f);
  const int half = (tid >> 7) & 1, c4 = tid & 127;
#pragma unroll
  for (int rr = half; rr < 32; rr += 2) {
    const int r = t0 + rr;
    if (r >= total)
      *(float4*)(res + ((size_t)b * TOUT_ + r) * C_ + c4 * 4) = z4;
  }
}

// ---------------------------------------------------------------------------
// 1) prep (256 threads): cvt_x_pad (0..4127, XCD-banded) +
//    cvt W1 (4128..4895) + cvt W2 (4896..5663) + csum (5664..5695)
//    Banding: cvt pair p = (bx&7)*516 + (bx>>3) -> rows [1032*xcd, +1032):
//    exactly the xpad band conv1's XCD xcd stages (b in [4*xcd, 4*xcd+4)).
// ---------------------------------------------------------------------------
__global__ __launch_bounds__(256) void prep_kernel(const float* __restrict__ X,
                                                   const float* __restrict__ W1,
                                                   const float* __restrict__ W2,
                                                   const int* __restrict__ dur,
                                                   __hip_bfloat16* __restrict__ xpad,
                                                   __hip_bfloat16* __restrict__ hpad,
                                                   __hip_bfloat16* __restrict__ Wt1,
                                                   __hip_bfloat16* __restrict__ Wt2,
                                                   int* __restrict__ csum) {
  __shared__ float tile[32 * 33];
  const int tid = threadIdx.x;
  if (blockIdx.x >= 5664) {
    csum_block(dur, csum, blockIdx.x - 5664, tid, (int*)tile);
    return;
  }
  if (blockIdx.x >= 4896) {
    const int id = blockIdx.x - 4896;       // 0..767
    wt_convert_block(W2, Wt2, (id % 48) * 32, (id / 48) * 32, tid, tile);
    return;
  }
  if (blockIdx.x >= 4128) {
    const int id = blockIdx.x - 4128;       // 0..767
    wt_convert_block(W1, Wt1, (id % 48) * 32, (id / 48) * 32, tid, tile);
    return;
  }
  // XCD-banded x-conversion: pair p covers rows 2p, 2p+1
  const int bx = blockIdx.x;
  const int p  = (bx & 7) * 516 + (bx >> 3);     // bijective on [0,4128)
  const int row = p * 2 + (tid >> 7);            // 0..8255
  const int b = row / TP_;
  const int t = row - b * TP_;
  const int c = (tid & 127) * 4;
  __hip_bfloat16* dst = xpad + (size_t)row * C_ + c;
  if (t == 0 || t == TP_ - 1) {
    ushort4 zz = make_ushort4(0, 0, 0, 0);
    *(ushort4*)dst = zz;
    *(ushort4*)(hpad + (size_t)row * C_ + c) = zz;
    return;
  }
  const float4 v = *(const float4*)(X + (size_t)(b * T_ + t - 1) * C_ + c);
  union { __hip_bfloat16 h[4]; ushort4 u; } o;
  o.h[0] = __float2bfloat16(v.x);
  o.h[1] = __float2bfloat16(v.y);
  o.h[2] = __float2bfloat16(v.z);
  o.h[3] = __float2bfloat16(v.w);
  *(ushort4*)dst = o.u;
}

// ---------------------------------------------------------------------------
// 2) heterogeneous, 512 threads/block (R21-champion structure):
//    conv GEMM (0..255, XCD-banded tiles) || expand (256..895, 2 units/block)
//    conv: 128(M)x128(N), BK=64 (two 32-k slabs), 24 steps, 8 waves of 64x32,
//    2-buf ring (64 KB LDS), counted vmcnt(4), line-coalesced staging.
// ---------------------------------------------------------------------------
__global__ __launch_bounds__(512) void conv_expand_kernel(
    const __hip_bfloat16* __restrict__ Apad,   // [32*258, 512]
    const __hip_bfloat16* __restrict__ Wt,     // [512, 1536]
    const float* __restrict__ bias,            // [512]
    __hip_bfloat16* __restrict__ Y,            // [8192, 512] bf16
    const float* __restrict__ X,               // f32 input (for expand)
    const int* __restrict__ csum,
    float* __restrict__ res,
    int ex_base) {
  __shared__ __hip_bfloat16 smA[2][2][4096];   // [buf][slab][row128*32] = 32 KB
  __shared__ __hip_bfloat16 smB[2][2][4096];   // [buf][slab][row128*32] = 32 KB

  const int tid = threadIdx.x;                 // 0..511

  if (blockIdx.x >= 256) {                     // expand: 2 units/block
    const int u = ex_base + (blockIdx.x - 256) * 2 + (tid >> 8);
    const int st = tid & 255;
    if (u < 512) expand_copy_block(X, csum, res, u, st);
    else         expand_zero_block(csum, res, u - 512, st);
    return;
  }

  // ---- conv GEMM path: 128(M) x 128(N), 8 waves of 64x32 ----
  const int lane = tid & 63;
  const int wid  = tid >> 6;                   // 0..7
  // XCD-aware remap (bijective on [0,256)): xcd = cid&7 keeps its band
  const int cid = blockIdx.x;
  const int xcd = cid & 7;
  const int idx = cid >> 3;                    // 0..31
  const int mt  = (xcd << 3) + (idx >> 2);     // 0..63
  const int nt  = idx & 3;                     // 0..3
  const int n0 = nt << 7;                      // 0,128,256,384
  const int m0 = mt << 7;                      // 0..8064
  const int b  = m0 >> 8;
  const int t0 = m0 & 255;                     // 0 or 128
  const int wm = (wid >> 2) << 6;              // 0 / 64
  const int wn = (wid & 3) << 5;               // 0,32,64,96

  // staging coords: 4 lanes/row, 16B each, within-line slot swizzle
  const int rowS = tid >> 2;                   // 0..127
  const int gsw  = ((tid & 3) + rowS) & 3;
  const __hip_bfloat16* arowA = Apad + (size_t)(b * TP_ + t0 + rowS) * C_ + (gsw << 3);
  const __hip_bfloat16* browB = Wt + (size_t)(n0 + rowS) * K_ + (gsw << 3);

  f32x4 acc[4][2] = {};

  // BK=64 never straddles a conv window (512 % 64 == 0); 4 GLL16/thread
  auto stage = [&](int buf, int k0) {
    const int kw = k0 >> 9;                    // conv window 0..2
    const int c0 = k0 & 511;
    const __hip_bfloat16* a0 = arowA + kw * C_ + c0;
    GLL16(a0,           &smA[buf][0][tid << 3]);
    GLL16(a0 + 32,      &smA[buf][1][tid << 3]);
    GLL16(browB + k0,      &smB[buf][0][tid << 3]);
    GLL16(browB + k0 + 32, &smB[buf][1][tid << 3]);
  };

  auto compute = [&](int buf) {
    const int g   = lane >> 4;
    const int r15 = lane & 15;
    const int sa  = ((g - r15) & 3) << 3;      // swizzled slot offset (elems)
#pragma unroll
    for (int sl = 0; sl < 2; ++sl) {
      const __hip_bfloat16* As = smA[buf][sl];
      const __hip_bfloat16* Bs = smB[buf][sl];
      bf16x8 aF[4], bF[2];
#pragma unroll
      for (int i = 0; i < 4; ++i)
        aF[i] = *(const bf16x8*)(As + ((wm + (i << 4) + r15) << 5) + sa);
#pragma unroll
      for (int i = 0; i < 2; ++i)
        bF[i] = *(const bf16x8*)(Bs + ((wn + (i << 4) + r15) << 5) + sa);
#pragma unroll
      for (int mi = 0; mi < 4; ++mi)
#pragma unroll
        for (int ni = 0; ni < 2; ++ni)
          acc[mi][ni] = __builtin_amdgcn_mfma_f32_16x16x32_bf16(
              aF[mi], bF[ni], acc[mi][ni], 0, 0, 0);
    }
  };

  // prologue: clean baseline, prefetch 2 tiles (8 vmem/wave in flight)
  asm volatile("s_waitcnt vmcnt(0)" ::: "memory");
  stage(0, 0);
  stage(1, 64);

  // main loop: compute tiles 0..21, stage tiles 2..23 (tile t -> buf t&1)
  for (int s = 0; s < 22; ++s) {
    asm volatile("s_waitcnt vmcnt(4)" ::: "memory");   // oldest tile's 4 done
    __builtin_amdgcn_sched_barrier(0);
    __builtin_amdgcn_s_barrier();
    compute(s & 1);
    asm volatile("s_waitcnt lgkmcnt(0)" ::: "memory");
    __builtin_amdgcn_s_barrier();
    stage(s & 1, (s + 2) << 6);
  }
  // tail: tiles 22 (buf0), 23 (buf1) — drain 4 -> 0
  asm volatile("s_waitcnt vmcnt(4)" ::: "memory");
  __builtin_amdgcn_sched_barrier(0);
  __builtin_amdgcn_s_barrier();
  compute(0);
  asm volatile("s_waitcnt vmcnt(0)" ::: "memory");
  __builtin_amdgcn_sched_barrier(0);
  __builtin_amdgcn_s_barrier();
  compute(1);

  // epilogue: C/D layout col = lane&15 (n), row = (lane>>4)*4 + reg (m)
  const int cn_base = n0 + wn + (lane & 15);
  const int rm_base = m0 + wm + ((lane >> 4) << 2);
#pragma unroll
  for (int ni = 0; ni < 2; ++ni) {
    const int cn = cn_base + (ni << 4);
    const float bb = bias[cn];
#pragma unroll
    for (int mi = 0; mi < 4; ++mi) {
#pragma unroll
      for (int rq = 0; rq < 4; ++rq) {
        const int rm = rm_base + (mi << 4) + rq;
        Y[(size_t)rm * H_ + cn] = __float2bfloat16(acc[mi][ni][rq] + bb);
      }
    }
  }
}

// ---------------------------------------------------------------------------
// 3) LayerNorm + ReLU: bf16 in -> bf16 out (padded layout), XCD-banded rows
//    (row band 1024*xcd..+1023 matches the conv band that wrote/will read it)
// ---------------------------------------------------------------------------
__global__ __launch_bounds__(256) void ln_relu_pad_kernel(
    const __hip_bfloat16* __restrict__ in,
    const float* __restrict__ g,
    const float* __restrict__ beta,
    __hip_bfloat16* __restrict__ outpad) {
  const int wave = threadIdx.x >> 6;
  const int lane = threadIdx.x & 63;
  const int bx = blockIdx.x;
  const int bi = (bx & 7) * 256 + (bx >> 3);   // bijective on [0,2048)
  const int row  = bi * 4 + wave;              // 0..8191, band = bx&7

  const bf16x8 hv = *(const bf16x8*)(in + (size_t)row * H_ + lane * 8);
  const __hip_bfloat16* hh = (const __hip_bfloat16*)&hv;
  float f[8];
#pragma unroll
  for (int j = 0; j < 8; ++j) f[j] = __bfloat162float(hh[j]);

  float s = 0.f, q = 0.f;
#pragma unroll
  for (int j = 0; j < 8; ++j) { s += f[j]; q += f[j] * f[j]; }
#pragma unroll
  for (int off = 32; off; off >>= 1) {
    s += __shfl_xor(s, off);
    q += __shfl_xor(q, off);
  }
  const float mu  = s * (1.0f / 512.0f);
  const float var = q * (1.0f / 512.0f) - mu * mu;
  const float rs  = rsqrtf(var + EPS_);

  const float4 g0 = *(const float4*)(g + lane * 8);
  const float4 g1 = *(const float4*)(g + lane * 8 + 4);
  const float4 e0 = *(const float4*)(beta + lane * 8);
  const float4 e1 = *(const float4*)(beta + lane * 8 + 4);
  const float gg[8] = {g0.x, g0.y, g0.z, g0.w, g1.x, g1.y, g1.z, g1.w};
  const float ee[8] = {e0.x, e0.y, e0.z, e0.w, e1.x, e1.y, e1.z, e1.w};

  union { __hip_bfloat16 h[8]; bf16x8 v; } o;
#pragma unroll
  for (int j = 0; j < 8; ++j)
    o.h[j] = __float2bfloat16(fmaxf(0.f, (f[j] - mu) * rs * gg[j] + ee[j]));

  const int bq = row >> 8, t = row & 255;
  *(bf16x8*)(outpad + (size_t)(bq * TP_ + t + 1) * H_ + lane * 8) = o.v;
}

// ---------------------------------------------------------------------------
// 4) LayerNorm + ReLU + linear head fused (bf16 in), XCD-banded rows
// ---------------------------------------------------------------------------
__global__ __launch_bounds__(256) void ln_relu_linear_kernel(
    const __hip_bfloat16* __restrict__ in,
    const float* __restrict__ g,
    const float* __restrict__ beta,
    const float* __restrict__ Wl,
    const float* __restrict__ bl,
    float* __restrict__ out) {
  const int wave = threadIdx.x >> 6;
  const int lane = threadIdx.x & 63;
  const int bx = blockIdx.x;
  const int bi = (bx & 7) * 256 + (bx >> 3);   // bijective on [0,2048)
  const int row  = bi * 4 + wave;

  const bf16x8 hv = *(const bf16x8*)(in + (size_t)row * H_ + lane * 8);
  const __hip_bfloat16* hh = (const __hip_bfloat16*)&hv;
  float f[8];
#pragma unroll
  for (int j = 0; j < 8; ++j) f[j] = __bfloat162float(hh[j]);

  float s = 0.f, q = 0.f;
#pragma unroll
  for (int j = 0; j < 8; ++j) { s += f[j]; q += f[j] * f[j]; }
#pragma unroll
  for (int off = 32; off; off >>= 1) {
    s += __shfl_xor(s, off);
    q += __shfl_xor(q, off);
  }
  const float mu  = s * (1.0f / 512.0f);
  const float var = q * (1.0f / 512.0f) - mu * mu;
  const float rs  = rsqrtf(var + EPS_);

  const float4 g0 = *(const float4*)(g + lane * 8);
  const float4 g1 = *(const float4*)(g + lane * 8 + 4);
  const float4 e0 = *(const float4*)(beta + lane * 8);
  const float4 e1 = *(const float4*)(beta + lane * 8 + 4);
  const float4 w0 = *(const float4*)(Wl + lane * 8);
  const float4 w1 = *(const float4*)(Wl + lane * 8 + 4);
  const float gg[8] = {g0.x, g0.y, g0.z, g0.w, g1.x, g1.y, g1.z, g1.w};
  const float ee[8] = {e0.x, e0.y, e0.z, e0.w, e1.x, e1.y, e1.z, e1.w};
  const float ww[8] = {w0.x, w0.y, w0.z, w0.w, w1.x, w1.y, w1.z, w1.w};

  float sd = 0.f;
#pragma unroll
  for (int j = 0; j < 8; ++j)
    sd += fmaxf(0.f, (f[j] - mu) * rs * gg[j] + ee[j]) * ww[j];
#pragma unroll
  for (int off = 32; off; off >>= 1) sd += __shfl_xor(sd, off);

  if (lane == 0) out[row] = sd + bl[0];
}

// ---------------------------------------------------------------------------
extern "C" void kernel_launch(void* const* d_in, const int* in_sizes, int n_in,
                              void* d_out, int out_size, void* d_ws, size_t ws_size,
                              hipStream_t stream) {
  const float* x     = (const float*)d_in[0];
  const int*   dur   = (const int*)d_in[1];
  const float* W1    = (const float*)d_in[2];
  const float* b1    = (const float*)d_in[3];
  const float* g1    = (const float*)d_in[4];
  const float* beta1 = (const float*)d_in[5];
  const float* W2    = (const float*)d_in[6];
  const float* b2    = (const float*)d_in[7];
  const float* g2    = (const float*)d_in[8];
  const float* beta2 = (const float*)d_in[9];
  const float* Wl    = (const float*)d_in[10];
  const float* bl    = (const float*)d_in[11];

  float* out = (float*)d_out;
  float* res    = out;                              // [B, TOUT, C]
  float* loglen = out + (size_t)B_ * TOUT_ * C_;    // [B, T]

  char* ws = (char*)d_ws;
  __hip_bfloat16* xpad = (__hip_bfloat16*)ws;                       // 8.45 MB
  __hip_bfloat16* hpad = xpad + (size_t)B_ * TP_ * C_;              // 8.45 MB
  __hip_bfloat16* Wt1  = hpad + (size_t)B_ * TP_ * C_;              // 1.57 MB
  __hip_bfloat16* Wt2  = Wt1 + (size_t)H_ * K_;                     // 1.57 MB
  __hip_bfloat16* tmp  = Wt2 + (size_t)H_ * K_;                     // 8.39 MB bf16
  int*   csum = (int*)(tmp + (size_t)B_ * T_ * H_);                 // 32 KB

  prep_kernel<<<5696, 256, 0, stream>>>(x, W1, W2, dur, xpad, hpad,
                                        Wt1, Wt2, csum);

  // conv1 (256) || expand units 0..1279 (640 blocks)
  conv_expand_kernel<<<896, 512, 0, stream>>>(xpad, Wt1, b1, tmp,
                                              x, csum, res, 0);
  ln_relu_pad_kernel<<<B_ * T_ / 4, 256, 0, stream>>>(tmp, g1, beta1, hpad);

  // conv2 (256) || expand units 1280..2559 (640 blocks)
  conv_expand_kernel<<<896, 512, 0, stream>>>(hpad, Wt2, b2, tmp,
                                              x, csum, res, 1280);
  ln_relu_linear_kernel<<<B_ * T_ / 4, 256, 0, stream>>>(tmp, g2, beta2, Wl, bl, loglen);
}

// Round 23
// 68.279 us; speedup vs baseline: 1.8860x; 1.0132x over previous
//
#include <hip/hip_runtime.h>
#include <hip/hip_bf16.h>

#define B_    32
#define T_    256
#define C_    512
#define H_    512
#define TOUT_ 2048
#define TP_   258        // padded time length (zero row at t=0 and t=257)
#define K_    1536       // 3 * 512
#define EPS_  1e-5f

typedef __attribute__((ext_vector_type(8))) short bf16x8;
typedef __attribute__((ext_vector_type(4))) float f32x4;

#define GLL16(g, l)                                                        \
  __builtin_amdgcn_global_load_lds(                                        \
      (const __attribute__((address_space(1))) void*)(g),                  \
      (__attribute__((address_space(3))) void*)(l), 16, 0, 0)

// ---------------------------------------------------------------------------
// helpers shared by heterogeneous kernels (operate on a 256-thread sub-tid)
// ---------------------------------------------------------------------------
__device__ __forceinline__ void wt_convert_block(const float* __restrict__ W,
                                                 __hip_bfloat16* __restrict__ Wt,
                                                 int k0, int n0, int tid,
                                                 float* tile /* [32][33] */) {
  const int tx = tid & 31;
  const int ty = tid >> 5;
#pragma unroll
  for (int i = 0; i < 4; ++i)
    tile[(ty * 4 + i) * 33 + tx] = W[(size_t)(k0 + ty * 4 + i) * H_ + n0 + tx];
  __syncthreads();
#pragma unroll
  for (int i = 0; i < 4; ++i)
    Wt[(size_t)(n0 + ty * 4 + i) * K_ + k0 + tx] =
        __float2bfloat16(tile[tx * 33 + ty * 4 + i]);
}

// inclusive scan of one batch's 256 durations -> csum (256-thread block)
__device__ __forceinline__ void csum_block(const int* __restrict__ dur,
                                           int* __restrict__ csum,
                                           int b, int tid, int* wsum) {
  int v = dur[b * T_ + tid];
#pragma unroll
  for (int off = 1; off < 64; off <<= 1) {
    int u = __shfl_up(v, off);
    if ((tid & 63) >= off) v += u;
  }
  if ((tid & 63) == 63) wsum[tid >> 6] = v;
  __syncthreads();
  int base = 0;
#pragma unroll
  for (int j = 0; j < 4; ++j)
    if (j < (tid >> 6)) base += wsum[j];
  csum[b * T_ + tid] = v + base;
}

// copy unit: 16 source rows; read row once, write its d output rows
__device__ __forceinline__ void expand_copy_block(const float* __restrict__ X,
                                                  const int* __restrict__ csum,
                                                  float* __restrict__ res,
                                                  int u, int tid) {
  const int wave = (tid >> 6) & 3, lane = tid & 63;
#pragma unroll
  for (int k = 0; k < 4; ++k) {
    const int sr = u * 16 + wave * 4 + k;    // 0..8191
    const int b = sr >> 8, t = sr & 255;
    const int* cb = csum + b * T_;
    const int c0 = t ? cb[t - 1] : 0;
    const int d  = cb[t] - c0;
    if (d == 0) continue;
    const float* src = X + (size_t)sr * C_;
    const float4 v0 = *(const float4*)(src + lane * 4);
    const float4 v1 = *(const float4*)(src + 256 + lane * 4);
    float* dst = res + ((size_t)b * TOUT_ + c0) * C_;
    for (int j = 0; j < d; ++j) {
      *(float4*)(dst + (size_t)j * C_ + lane * 4)       = v0;
      *(float4*)(dst + (size_t)j * C_ + 256 + lane * 4) = v1;
    }
  }
}

// zero unit: 32 output rows of one batch, zero those >= total
__device__ __forceinline__ void expand_zero_block(const int* __restrict__ csum,
                                                  float* __restrict__ res,
                                                  int z, int tid) {
  const int b  = z >> 6;
  const int t0 = (z & 63) << 5;
  const int total = csum[b * T_ + 255];
  const float4 z4 = make_float4(0.f, 0.f, 0.f, 0.f);
  const int half = (tid >> 7) & 1, c4 = tid & 127;
#pragma unroll
  for (int rr = half; rr < 32; rr += 2) {
    const int r = t0 + rr;
    if (r >= total)
      *(float4*)(res + ((size_t)b * TOUT_ + r) * C_ + c4 * 4) = z4;
  }
}

// ---------------------------------------------------------------------------
// 1) prep (256 threads): cvt_x_pad (0..4127, XCD-banded) +
//    cvt W1 (4128..4895) + cvt W2 (4896..5663) + csum (5664..5695)
// ---------------------------------------------------------------------------
__global__ __launch_bounds__(256) void prep_kernel(const float* __restrict__ X,
                                                   const float* __restrict__ W1,
                                                   const float* __restrict__ W2,
                                                   const int* __restrict__ dur,
                                                   __hip_bfloat16* __restrict__ xpad,
                                                   __hip_bfloat16* __restrict__ hpad,
                                                   __hip_bfloat16* __restrict__ Wt1,
                                                   __hip_bfloat16* __restrict__ Wt2,
                                                   int* __restrict__ csum) {
  __shared__ float tile[32 * 33];
  const int tid = threadIdx.x;
  if (blockIdx.x >= 5664) {
    csum_block(dur, csum, blockIdx.x - 5664, tid, (int*)tile);
    return;
  }
  if (blockIdx.x >= 4896) {
    const int id = blockIdx.x - 4896;       // 0..767
    wt_convert_block(W2, Wt2, (id % 48) * 32, (id / 48) * 32, tid, tile);
    return;
  }
  if (blockIdx.x >= 4128) {
    const int id = blockIdx.x - 4128;       // 0..767
    wt_convert_block(W1, Wt1, (id % 48) * 32, (id / 48) * 32, tid, tile);
    return;
  }
  // XCD-banded x-conversion: pair p covers rows 2p, 2p+1
  const int bx = blockIdx.x;
  const int p  = (bx & 7) * 516 + (bx >> 3);     // bijective on [0,4128)
  const int row = p * 2 + (tid >> 7);            // 0..8255
  const int b = row / TP_;
  const int t = row - b * TP_;
  const int c = (tid & 127) * 4;
  __hip_bfloat16* dst = xpad + (size_t)row * C_ + c;
  if (t == 0 || t == TP_ - 1) {
    ushort4 zz = make_ushort4(0, 0, 0, 0);
    *(ushort4*)dst = zz;
    *(ushort4*)(hpad + (size_t)row * C_ + c) = zz;
    return;
  }
  const float4 v = *(const float4*)(X + (size_t)(b * T_ + t - 1) * C_ + c);
  union { __hip_bfloat16 h[4]; ushort4 u; } o;
  o.h[0] = __float2bfloat16(v.x);
  o.h[1] = __float2bfloat16(v.y);
  o.h[2] = __float2bfloat16(v.z);
  o.h[3] = __float2bfloat16(v.w);
  *(ushort4*)dst = o.u;
}

// ---------------------------------------------------------------------------
// 2) heterogeneous, 512 threads/block (R22-champion structure):
//    conv GEMM (0..255, XCD-banded tiles) || expand (256..895, 2 units/block;
//    copy-unit pairs XCD-banded to match prep's X banding)
//    conv: 128(M)x128(N), BK=64 (two 32-k slabs), 24 steps, 8 waves of 64x32,
//    2-buf ring (64 KB LDS), counted vmcnt(4), line-coalesced staging.
// ---------------------------------------------------------------------------
__global__ __launch_bounds__(512) void conv_expand_kernel(
    const __hip_bfloat16* __restrict__ Apad,   // [32*258, 512]
    const __hip_bfloat16* __restrict__ Wt,     // [512, 1536]
    const float* __restrict__ bias,            // [512]
    __hip_bfloat16* __restrict__ Y,            // [8192, 512] bf16
    const float* __restrict__ X,               // f32 input (for expand)
    const int* __restrict__ csum,
    float* __restrict__ res,
    int ex_base) {
  __shared__ __hip_bfloat16 smA[2][2][4096];   // [buf][slab][row128*32] = 32 KB
  __shared__ __hip_bfloat16 smB[2][2][4096];   // [buf][slab][row128*32] = 32 KB

  const int tid = threadIdx.x;                 // 0..511

  if (blockIdx.x >= 256) {                     // expand: 2 units/block
    const int e = blockIdx.x - 256;            // 0..639
    // band the copy sub-range (e<256 when ex_base==0): pair j' covers
    // units [2j', 2j'+2); j' = (e&7)*32 + (e>>3) puts batches 4x..4x+3
    // on XCD x (matches prep's X/xpad banding). zeros: identity.
    const int j = (ex_base == 0 && e < 256) ? ((e & 7) * 32 + (e >> 3)) : e;
    const int u = ex_base + j * 2 + (tid >> 8);
    const int st = tid & 255;
    if (u < 512) expand_copy_block(X, csum, res, u, st);
    else         expand_zero_block(csum, res, u - 512, st);
    return;
  }

  // ---- conv GEMM path: 128(M) x 128(N), 8 waves of 64x32 ----
  const int lane = tid & 63;
  const int wid  = tid >> 6;                   // 0..7
  // XCD-aware remap (bijective on [0,256)): xcd = cid&7 keeps its band
  const int cid = blockIdx.x;
  const int xcd = cid & 7;
  const int idx = cid >> 3;                    // 0..31
  const int mt  = (xcd << 3) + (idx >> 2);     // 0..63
  const int nt  = idx & 3;                     // 0..3
  const int n0 = nt << 7;                      // 0,128,256,384
  const int m0 = mt << 7;                      // 0..8064
  const int b  = m0 >> 8;
  const int t0 = m0 & 255;                     // 0 or 128
  const int wm = (wid >> 2) << 6;              // 0 / 64
  const int wn = (wid & 3) << 5;               // 0,32,64,96

  // staging coords: 4 lanes/row, 16B each, within-line slot swizzle
  const int rowS = tid >> 2;                   // 0..127
  const int gsw  = ((tid & 3) + rowS) & 3;
  const __hip_bfloat16* arowA = Apad + (size_t)(b * TP_ + t0 + rowS) * C_ + (gsw << 3);
  const __hip_bfloat16* browB = Wt + (size_t)(n0 + rowS) * K_ + (gsw << 3);

  f32x4 acc[4][2] = {};

  // BK=64 never straddles a conv window (512 % 64 == 0); 4 GLL16/thread
  auto stage = [&](int buf, int k0) {
    const int kw = k0 >> 9;                    // conv window 0..2
    const int c0 = k0 & 511;
    const __hip_bfloat16* a0 = arowA + kw * C_ + c0;
    GLL16(a0,           &smA[buf][0][tid << 3]);
    GLL16(a0 + 32,      &smA[buf][1][tid << 3]);
    GLL16(browB + k0,      &smB[buf][0][tid << 3]);
    GLL16(browB + k0 + 32, &smB[buf][1][tid << 3]);
  };

  auto compute = [&](int buf) {
    const int g   = lane >> 4;
    const int r15 = lane & 15;
    const int sa  = ((g - r15) & 3) << 3;      // swizzled slot offset (elems)
#pragma unroll
    for (int sl = 0; sl < 2; ++sl) {
      const __hip_bfloat16* As = smA[buf][sl];
      const __hip_bfloat16* Bs = smB[buf][sl];
      bf16x8 aF[4], bF[2];
#pragma unroll
      for (int i = 0; i < 4; ++i)
        aF[i] = *(const bf16x8*)(As + ((wm + (i << 4) + r15) << 5) + sa);
#pragma unroll
      for (int i = 0; i < 2; ++i)
        bF[i] = *(const bf16x8*)(Bs + ((wn + (i << 4) + r15) << 5) + sa);
#pragma unroll
      for (int mi = 0; mi < 4; ++mi)
#pragma unroll
        for (int ni = 0; ni < 2; ++ni)
          acc[mi][ni] = __builtin_amdgcn_mfma_f32_16x16x32_bf16(
              aF[mi], bF[ni], acc[mi][ni], 0, 0, 0);
    }
  };

  // prologue: clean baseline, prefetch 2 tiles (8 vmem/wave in flight)
  asm volatile("s_waitcnt vmcnt(0)" ::: "memory");
  stage(0, 0);
  stage(1, 64);

  // main loop: compute tiles 0..21, stage tiles 2..23 (tile t -> buf t&1)
  for (int s = 0; s < 22; ++s) {
    asm volatile("s_waitcnt vmcnt(4)" ::: "memory");   // oldest tile's 4 done
    __builtin_amdgcn_sched_barrier(0);
    __builtin_amdgcn_s_barrier();
    compute(s & 1);
    asm volatile("s_waitcnt lgkmcnt(0)" ::: "memory");
    __builtin_amdgcn_s_barrier();
    stage(s & 1, (s + 2) << 6);
  }
  // tail: tiles 22 (buf0), 23 (buf1) — drain 4 -> 0
  asm volatile("s_waitcnt vmcnt(4)" ::: "memory");
  __builtin_amdgcn_sched_barrier(0);
  __builtin_amdgcn_s_barrier();
  compute(0);
  asm volatile("s_waitcnt vmcnt(0)" ::: "memory");
  __builtin_amdgcn_sched_barrier(0);
  __builtin_amdgcn_s_barrier();
  compute(1);

  // epilogue: C/D layout col = lane&15 (n), row = (lane>>4)*4 + reg (m)
  const int cn_base = n0 + wn + (lane & 15);
  const int rm_base = m0 + wm + ((lane >> 4) << 2);
#pragma unroll
  for (int ni = 0; ni < 2; ++ni) {
    const int cn = cn_base + (ni << 4);
    const float bb = bias[cn];
#pragma unroll
    for (int mi = 0; mi < 4; ++mi) {
#pragma unroll
      for (int rq = 0; rq < 4; ++rq) {
        const int rm = rm_base + (mi << 4) + rq;
        Y[(size_t)rm * H_ + cn] = __float2bfloat16(acc[mi][ni][rq] + bb);
      }
    }
  }
}

// ---------------------------------------------------------------------------
// 3) LayerNorm + ReLU: bf16 in -> bf16 out (padded layout), XCD-banded rows
// ---------------------------------------------------------------------------
__global__ __launch_bounds__(256) void ln_relu_pad_kernel(
    const __hip_bfloat16* __restrict__ in,
    const float* __restrict__ g,
    const float* __restrict__ beta,
    __hip_bfloat16* __restrict__ outpad) {
  const int wave = threadIdx.x >> 6;
  const int lane = threadIdx.x & 63;
  const int bx = blockIdx.x;
  const int bi = (bx & 7) * 256 + (bx >> 3);   // bijective on [0,2048)
  const int row  = bi * 4 + wave;              // 0..8191, band = bx&7

  const bf16x8 hv = *(const bf16x8*)(in + (size_t)row * H_ + lane * 8);
  const __hip_bfloat16* hh = (const __hip_bfloat16*)&hv;
  float f[8];
#pragma unroll
  for (int j = 0; j < 8; ++j) f[j] = __bfloat162float(hh[j]);

  float s = 0.f, q = 0.f;
#pragma unroll
  for (int j = 0; j < 8; ++j) { s += f[j]; q += f[j] * f[j]; }
#pragma unroll
  for (int off = 32; off; off >>= 1) {
    s += __shfl_xor(s, off);
    q += __shfl_xor(q, off);
  }
  const float mu  = s * (1.0f / 512.0f);
  const float var = q * (1.0f / 512.0f) - mu * mu;
  const float rs  = rsqrtf(var + EPS_);

  const float4 g0 = *(const float4*)(g + lane * 8);
  const float4 g1 = *(const float4*)(g + lane * 8 + 4);
  const float4 e0 = *(const float4*)(beta + lane * 8);
  const float4 e1 = *(const float4*)(beta + lane * 8 + 4);
  const float gg[8] = {g0.x, g0.y, g0.z, g0.w, g1.x, g1.y, g1.z, g1.w};
  const float ee[8] = {e0.x, e0.y, e0.z, e0.w, e1.x, e1.y, e1.z, e1.w};

  union { __hip_bfloat16 h[8]; bf16x8 v; } o;
#pragma unroll
  for (int j = 0; j < 8; ++j)
    o.h[j] = __float2bfloat16(fmaxf(0.f, (f[j] - mu) * rs * gg[j] + ee[j]));

  const int bq = row >> 8, t = row & 255;
  *(bf16x8*)(outpad + (size_t)(bq * TP_ + t + 1) * H_ + lane * 8) = o.v;
}

// ---------------------------------------------------------------------------
// 4) LayerNorm + ReLU + linear head fused (bf16 in), XCD-banded rows
// ---------------------------------------------------------------------------
__global__ __launch_bounds__(256) void ln_relu_linear_kernel(
    const __hip_bfloat16* __restrict__ in,
    const float* __restrict__ g,
    const float* __restrict__ beta,
    const float* __restrict__ Wl,
    const float* __restrict__ bl,
    float* __restrict__ out) {
  const int wave = threadIdx.x >> 6;
  const int lane = threadIdx.x & 63;
  const int bx = blockIdx.x;
  const int bi = (bx & 7) * 256 + (bx >> 3);   // bijective on [0,2048)
  const int row  = bi * 4 + wave;

  const bf16x8 hv = *(const bf16x8*)(in + (size_t)row * H_ + lane * 8);
  const __hip_bfloat16* hh = (const __hip_bfloat16*)&hv;
  float f[8];
#pragma unroll
  for (int j = 0; j < 8; ++j) f[j] = __bfloat162float(hh[j]);

  float s = 0.f, q = 0.f;
#pragma unroll
  for (int j = 0; j < 8; ++j) { s += f[j]; q += f[j] * f[j]; }
#pragma unroll
  for (int off = 32; off; off >>= 1) {
    s += __shfl_xor(s, off);
    q += __shfl_xor(q, off);
  }
  const float mu  = s * (1.0f / 512.0f);
  const float var = q * (1.0f / 512.0f) - mu * mu;
  const float rs  = rsqrtf(var + EPS_);

  const float4 g0 = *(const float4*)(g + lane * 8);
  const float4 g1 = *(const float4*)(g + lane * 8 + 4);
  const float4 e0 = *(const float4*)(beta + lane * 8);
  const float4 e1 = *(const float4*)(beta + lane * 8 + 4);
  const float4 w0 = *(const float4*)(Wl + lane * 8);
  const float4 w1 = *(const float4*)(Wl + lane * 8 + 4);
  const float gg[8] = {g0.x, g0.y, g0.z, g0.w, g1.x, g1.y, g1.z, g1.w};
  const float ee[8] = {e0.x, e0.y, e0.z, e0.w, e1.x, e1.y, e1.z, e1.w};
  const float ww[8] = {w0.x, w0.y, w0.z, w0.w, w1.x, w1.y, w1.z, w1.w};

  float sd = 0.f;
#pragma unroll
  for (int j = 0; j < 8; ++j)
    sd += fmaxf(0.f, (f[j] - mu) * rs * gg[j] + ee[j]) * ww[j];
#pragma unroll
  for (int off = 32; off; off >>= 1) sd += __shfl_xor(sd, off);

  if (lane == 0) out[row] = sd + bl[0];
}

// ---------------------------------------------------------------------------
extern "C" void kernel_launch(void* const* d_in, const int* in_sizes, int n_in,
                              void* d_out, int out_size, void* d_ws, size_t ws_size,
                              hipStream_t stream) {
  const float* x     = (const float*)d_in[0];
  const int*   dur   = (const int*)d_in[1];
  const float* W1    = (const float*)d_in[2];
  const float* b1    = (const float*)d_in[3];
  const float* g1    = (const float*)d_in[4];
  const float* beta1 = (const float*)d_in[5];
  const float* W2    = (const float*)d_in[6];
  const float* b2    = (const float*)d_in[7];
  const float* g2    = (const float*)d_in[8];
  const float* beta2 = (const float*)d_in[9];
  const float* Wl    = (const float*)d_in[10];
  const float* bl    = (const float*)d_in[11];

  float* out = (float*)d_out;
  float* res    = out;                              // [B, TOUT, C]
  float* loglen = out + (size_t)B_ * TOUT_ * C_;    // [B, T]

  char* ws = (char*)d_ws;
  __hip_bfloat16* xpad = (__hip_bfloat16*)ws;                       // 8.45 MB
  __hip_bfloat16* hpad = xpad + (size_t)B_ * TP_ * C_;              // 8.45 MB
  __hip_bfloat16* Wt1  = hpad + (size_t)B_ * TP_ * C_;              // 1.57 MB
  __hip_bfloat16* Wt2  = Wt1 + (size_t)H_ * K_;                     // 1.57 MB
  __hip_bfloat16* tmp  = Wt2 + (size_t)H_ * K_;                     // 8.39 MB bf16
  int*   csum = (int*)(tmp + (size_t)B_ * T_ * H_);                 // 32 KB

  prep_kernel<<<5696, 256, 0, stream>>>(x, W1, W2, dur, xpad, hpad,
                                        Wt1, Wt2, csum);

  // conv1 (256) || expand units 0..1279 (640 blocks, copies banded)
  conv_expand_kernel<<<896, 512, 0, stream>>>(xpad, Wt1, b1, tmp,
                                              x, csum, res, 0);
  ln_relu_pad_kernel<<<B_ * T_ / 4, 256, 0, stream>>>(tmp, g1, beta1, hpad);

  // conv2 (256) || expand units 1280..2559 (640 blocks)
  conv_expand_kernel<<<896, 512, 0, stream>>>(hpad, Wt2, b2, tmp,
                                              x, csum, res, 1280);
  ln_relu_linear_kernel<<<B_ * T_ / 4, 256, 0, stream>>>(tmp, g2, beta2, Wl, bl, loglen);
}